// Round 1
// baseline (845.196 us; speedup 1.0000x reference)
//
#include <hip/hip_runtime.h>
#include <cstdint>
#include <cstddef>

#define DF 128

// ---------------- edge dtype handling (int32 vs int64 storage) ----------------
__device__ __forceinline__ int edge_at(const void* ei, long long idx, int is32) {
  return is32 ? ((const int*)ei)[idx] : (int)((const long long*)ei)[idx];
}

// If the buffer is int64 (values < 2^31), every odd 32-bit word is a zero hi-half.
// If int32, odd words are random node ids (virtually never all zero).
__global__ void detect_dtype_kernel(const unsigned* __restrict__ ei, long long nelem,
                                    int* __restrict__ flag) {
  long long half = nelem / 2;
  int t = threadIdx.x + blockIdx.x * blockDim.x;
  long long step = (half + 2047) / 2048;
  long long k = (long long)t * step;
  if (k < half && ei[2 * k + 1] != 0) atomicOr(flag, 1);
}

// ---------------- degrees + norms ----------------
__global__ void degree_kernel(const void* __restrict__ ei, long long E,
                              int* __restrict__ degs, int* __restrict__ degd,
                              const int* __restrict__ flag) {
  int is32 = *flag;
  long long e = (long long)blockIdx.x * blockDim.x + threadIdx.x;
  if (e >= E) return;
  atomicAdd(&degs[edge_at(ei, e, is32)], 1);
  atomicAdd(&degd[edge_at(ei, E + e, is32)], 1);
}

__global__ void norm_kernel(const int* __restrict__ degs, const int* __restrict__ degd,
                            float* __restrict__ nout, float* __restrict__ nin, int n) {
  int i = blockIdx.x * blockDim.x + threadIdx.x;
  if (i >= n) return;
  nout[i] = rsqrtf((float)(degs[i] > 1 ? degs[i] : 1));
  nin[i]  = rsqrtf((float)(degd[i] > 1 ? degd[i] : 1));
}

// ---------------- exclusive scan (3-kernel, shfl-based) ----------------
__device__ __forceinline__ int wave_incl_scan(int v, int lane) {
#pragma unroll
  for (int off = 1; off < 64; off <<= 1) {
    int t = __shfl_up(v, off, 64);
    if (lane >= off) v += t;
  }
  return v;
}

__global__ void chunk_sum_kernel(const int* __restrict__ deg, int* __restrict__ partials, int n) {
  __shared__ int wsum[16];
  int tid = threadIdx.x, lane = tid & 63, wid = tid >> 6;
  int base = blockIdx.x * 4096 + tid * 4;
  int s = 0;
#pragma unroll
  for (int q = 0; q < 4; ++q) { int i = base + q; if (i < n) s += deg[i]; }
#pragma unroll
  for (int off = 32; off; off >>= 1) s += __shfl_down(s, off, 64);
  if (lane == 0) wsum[wid] = s;
  __syncthreads();
  if (tid == 0) {
    int t = 0;
#pragma unroll
    for (int w = 0; w < 16; ++w) t += wsum[w];
    partials[blockIdx.x] = t;
  }
}

__global__ void scan_partials_kernel(int* __restrict__ partials, int nb) {
  int lane = threadIdx.x;
  int carry = 0;
  for (int base = 0; base < nb; base += 64) {
    int i = base + lane;
    int v = (i < nb) ? partials[i] : 0;
    int s = wave_incl_scan(v, lane);
    if (i < nb) partials[i] = s - v + carry;  // exclusive + carry
    carry += __shfl(s, 63, 64);
  }
}

__global__ void scan_chunk_kernel(const int* __restrict__ deg, const int* __restrict__ chunk_off,
                                  int* __restrict__ row_ptr, int n) {
  __shared__ int wsum[16];
  int tid = threadIdx.x, lane = tid & 63, wid = tid >> 6;
  int base = blockIdx.x * 4096 + tid * 4;
  int v0 = (base + 0 < n) ? deg[base + 0] : 0;
  int v1 = (base + 1 < n) ? deg[base + 1] : 0;
  int v2 = (base + 2 < n) ? deg[base + 2] : 0;
  int v3 = (base + 3 < n) ? deg[base + 3] : 0;
  int p0 = v0, p1 = p0 + v1, p2 = p1 + v2, p3 = p2 + v3;
  int ws = wave_incl_scan(p3, lane);
  if (lane == 63) wsum[wid] = ws;
  __syncthreads();
  if (wid == 0) {
    int x = (lane < 16) ? wsum[lane] : 0;
    x = wave_incl_scan(x, lane);
    if (lane < 16) wsum[lane] = x;
  }
  __syncthreads();
  int off = (wid > 0 ? wsum[wid - 1] : 0) + (ws - p3) + chunk_off[blockIdx.x];
  if (base + 0 < n) row_ptr[base + 1] = off + p0;
  if (base + 1 < n) row_ptr[base + 2] = off + p1;
  if (base + 2 < n) row_ptr[base + 3] = off + p2;
  if (base + 3 < n) row_ptr[base + 4] = off + p3;
  if (blockIdx.x == 0 && tid == 0) row_ptr[0] = 0;
}

__global__ void copy_int_kernel(const int* __restrict__ a, int* __restrict__ b, int n) {
  int i = blockIdx.x * blockDim.x + threadIdx.x;
  if (i < n) b[i] = a[i];
}

__global__ void fill_csr_kernel(const void* __restrict__ ei, long long E,
                                int* __restrict__ cursor, int* __restrict__ csr_src,
                                const int* __restrict__ flag) {
  int is32 = *flag;
  long long e = (long long)blockIdx.x * blockDim.x + threadIdx.x;
  if (e >= E) return;
  int s = edge_at(ei, e, is32);
  int d = edge_at(ei, E + e, is32);
  int p = atomicAdd(&cursor[d], 1);
  csr_src[p] = s;
}

// ---------------- aggregation: one wave per destination node ----------------
__global__ void aggregate_kernel(const float* __restrict__ x, const float* __restrict__ nout,
                                 const int* __restrict__ row_ptr, const int* __restrict__ csr_src,
                                 float* __restrict__ agg, int n) {
  int wave = blockIdx.x * (blockDim.x >> 6) + (threadIdx.x >> 6);
  int lane = threadIdx.x & 63;
  if (wave >= n) return;
  int beg = row_ptr[wave], end = row_ptr[wave + 1];
  float ax = 0.f, ay = 0.f;
  for (int j = beg; j < end; ++j) {
    int s = csr_src[j];
    float sc = nout[s];
    float2 v = *(const float2*)(x + (size_t)s * DF + lane * 2);
    ax += v.x * sc;
    ay += v.y * sc;
  }
  float2 r; r.x = ax; r.y = ay;
  *(float2*)(agg + (size_t)wave * DF + lane * 2) = r;
}

// ---------------- row-wise transform: out[i,:] = din[i]*(agg[i,:]@W) + b ----------------
__global__ __launch_bounds__(256) void transform_kernel(
    const float* __restrict__ agg, const float* __restrict__ nin,
    const float* __restrict__ W, const float* __restrict__ bias,
    float* __restrict__ out, int n) {
  __shared__ float Ws[DF * DF];     // 64 KiB
  __shared__ float rows[8][DF];     // 4 KiB
  for (int i = threadIdx.x; i < DF * DF / 4; i += 256)
    ((float4*)Ws)[i] = ((const float4*)W)[i];
  int j = threadIdx.x & 127;
  int half = threadIdx.x >> 7;
  float bj = bias[j];
  int ngroups = (n + 7) / 8;
  for (int g = blockIdx.x; g < ngroups; g += gridDim.x) {
    int row0 = g * 8;
    __syncthreads();  // also covers initial Ws load
    {
      int rr = threadIdx.x >> 5, cc = threadIdx.x & 31;
      int row = row0 + rr;
      float4 v = {0.f, 0.f, 0.f, 0.f};
      if (row < n) v = ((const float4*)(agg + (size_t)row * DF))[cc];
      ((float4*)&rows[rr][0])[cc] = v;
    }
    __syncthreads();
    float a0 = 0.f, a1 = 0.f, a2 = 0.f, a3 = 0.f;
#pragma unroll 8
    for (int k = 0; k < DF; ++k) {
      float w = Ws[k * DF + j];
      a0 += rows[half + 0][k] * w;
      a1 += rows[half + 2][k] * w;
      a2 += rows[half + 4][k] * w;
      a3 += rows[half + 6][k] * w;
    }
    int r0 = row0 + half;
    if (r0 < n)     out[(size_t)r0 * DF + j]       = a0 * nin[r0] + bj;
    if (r0 + 2 < n) out[(size_t)(r0 + 2) * DF + j] = a1 * nin[r0 + 2] + bj;
    if (r0 + 4 < n) out[(size_t)(r0 + 4) * DF + j] = a2 * nin[r0 + 4] + bj;
    if (r0 + 6 < n) out[(size_t)(r0 + 6) * DF + j] = a3 * nin[r0 + 6] + bj;
  }
}

extern "C" void kernel_launch(void* const* d_in, const int* in_sizes, int n_in,
                              void* d_out, int out_size, void* d_ws, size_t ws_size,
                              hipStream_t stream) {
  const float* in_feat = (const float*)d_in[0];
  const void*  ei      = d_in[1];
  const float* W1 = (const float*)d_in[2];
  const float* b1 = (const float*)d_in[3];
  const float* W2 = (const float*)d_in[4];
  const float* b2 = (const float*)d_in[5];
  float* out = (float*)d_out;

  const int N = in_sizes[0] / DF;
  const long long E = in_sizes[1] / 2;
  const int NB = (N + 4095) / 4096;

  size_t off = 0;
  auto take = [&](size_t nb) -> char* {
    char* p = (char*)d_ws + off;
    off += (nb + 255) & ~(size_t)255;
    return p;
  };
  float* agg    = (float*)take((size_t)N * DF * 4);  // 51.2 MB
  int* degs     = (int*)take((size_t)N * 4);
  int* degd     = (int*)take((size_t)N * 4);
  float* nout   = (float*)take((size_t)N * 4);
  float* nin    = (float*)take((size_t)N * 4);
  int* row_ptr  = (int*)take((size_t)(N + 1) * 4);
  int* cursor   = (int*)take((size_t)N * 4);
  int* partials = (int*)take((size_t)NB * 4);
  int* flag     = (int*)take(4);
  int* csr_src  = (int*)take((size_t)E * 4);         // 6.4 MB
  (void)ws_size; (void)n_in; (void)out_size;

  hipMemsetAsync(degs, 0, (size_t)N * 4, stream);
  hipMemsetAsync(degd, 0, (size_t)N * 4, stream);
  hipMemsetAsync(flag, 0, 4, stream);

  detect_dtype_kernel<<<8, 256, 0, stream>>>((const unsigned*)ei, (long long)in_sizes[1], flag);

  int eb = (int)((E + 255) / 256);
  int nb256 = (N + 255) / 256;

  degree_kernel<<<eb, 256, 0, stream>>>(ei, E, degs, degd, flag);
  norm_kernel<<<nb256, 256, 0, stream>>>(degs, degd, nout, nin, N);

  chunk_sum_kernel<<<NB, 1024, 0, stream>>>(degd, partials, N);
  scan_partials_kernel<<<1, 64, 0, stream>>>(partials, NB);
  scan_chunk_kernel<<<NB, 1024, 0, stream>>>(degd, partials, row_ptr, N);
  copy_int_kernel<<<nb256, 256, 0, stream>>>(row_ptr, cursor, N);
  fill_csr_kernel<<<eb, 256, 0, stream>>>(ei, E, cursor, csr_src, flag);

  int ab = (N + 3) / 4;  // 4 waves (nodes) per 256-thread block
  // conv1: in_feat -> agg -> h1 (stored in d_out)
  aggregate_kernel<<<ab, 256, 0, stream>>>(in_feat, nout, row_ptr, csr_src, agg, N);
  transform_kernel<<<2048, 256, 0, stream>>>(agg, nin, W1, b1, out, N);
  // conv2: h1 (d_out) -> agg -> out (d_out, overwritten after reads complete)
  aggregate_kernel<<<ab, 256, 0, stream>>>(out, nout, row_ptr, csr_src, agg, N);
  transform_kernel<<<2048, 256, 0, stream>>>(agg, nin, W2, b2, out, N);
}

// Round 3
// 629.118 us; speedup vs baseline: 1.3435x; 1.3435x over previous
//
#include <hip/hip_runtime.h>
#include <cstdint>
#include <cstddef>

#define DF 128

// ---------------- edge dtype handling (int32 vs int64 storage) ----------------
__device__ __forceinline__ int edge_at(const void* ei, long long idx, int is32) {
  return is32 ? ((const int*)ei)[idx] : (int)((const long long*)ei)[idx];
}

__global__ void detect_dtype_kernel(const unsigned* __restrict__ ei, long long nelem,
                                    int* __restrict__ flag) {
  long long half = nelem / 2;
  int t = threadIdx.x + blockIdx.x * blockDim.x;
  long long step = (half + 2047) / 2048;
  long long k = (long long)t * step;
  if (k < half && ei[2 * k + 1] != 0) atomicOr(flag, 1);
}

// ---------------- degrees + norms ----------------
__global__ void degree_kernel(const void* __restrict__ ei, long long E,
                              int* __restrict__ degs, int* __restrict__ degd,
                              const int* __restrict__ flag) {
  int is32 = *flag;
  long long e = (long long)blockIdx.x * blockDim.x + threadIdx.x;
  if (e >= E) return;
  atomicAdd(&degs[edge_at(ei, e, is32)], 1);
  atomicAdd(&degd[edge_at(ei, E + e, is32)], 1);
}

__global__ void norm_kernel(const int* __restrict__ degs, const int* __restrict__ degd,
                            float* __restrict__ nout, float* __restrict__ nin, int n) {
  int i = blockIdx.x * blockDim.x + threadIdx.x;
  if (i >= n) return;
  nout[i] = rsqrtf((float)(degs[i] > 1 ? degs[i] : 1));
  nin[i]  = rsqrtf((float)(degd[i] > 1 ? degd[i] : 1));
}

// ---------------- exclusive scan (3-kernel, shfl-based) ----------------
__device__ __forceinline__ int wave_incl_scan(int v, int lane) {
#pragma unroll
  for (int off = 1; off < 64; off <<= 1) {
    int t = __shfl_up(v, off, 64);
    if (lane >= off) v += t;
  }
  return v;
}

__global__ void chunk_sum_kernel(const int* __restrict__ deg, int* __restrict__ partials, int n) {
  __shared__ int wsum[16];
  int tid = threadIdx.x, lane = tid & 63, wid = tid >> 6;
  int base = blockIdx.x * 4096 + tid * 4;
  int s = 0;
#pragma unroll
  for (int q = 0; q < 4; ++q) { int i = base + q; if (i < n) s += deg[i]; }
#pragma unroll
  for (int off = 32; off; off >>= 1) s += __shfl_down(s, off, 64);
  if (lane == 0) wsum[wid] = s;
  __syncthreads();
  if (tid == 0) {
    int t = 0;
#pragma unroll
    for (int w = 0; w < 16; ++w) t += wsum[w];
    partials[blockIdx.x] = t;
  }
}

__global__ void scan_partials_kernel(int* __restrict__ partials, int nb) {
  int lane = threadIdx.x;
  int carry = 0;
  for (int base = 0; base < nb; base += 64) {
    int i = base + lane;
    int v = (i < nb) ? partials[i] : 0;
    int s = wave_incl_scan(v, lane);
    if (i < nb) partials[i] = s - v + carry;  // exclusive + carry
    carry += __shfl(s, 63, 64);
  }
}

__global__ void scan_chunk_kernel(const int* __restrict__ deg, const int* __restrict__ chunk_off,
                                  int* __restrict__ row_ptr, int n) {
  __shared__ int wsum[16];
  int tid = threadIdx.x, lane = tid & 63, wid = tid >> 6;
  int base = blockIdx.x * 4096 + tid * 4;
  int v0 = (base + 0 < n) ? deg[base + 0] : 0;
  int v1 = (base + 1 < n) ? deg[base + 1] : 0;
  int v2 = (base + 2 < n) ? deg[base + 2] : 0;
  int v3 = (base + 3 < n) ? deg[base + 3] : 0;
  int p0 = v0, p1 = p0 + v1, p2 = p1 + v2, p3 = p2 + v3;
  int ws = wave_incl_scan(p3, lane);
  if (lane == 63) wsum[wid] = ws;
  __syncthreads();
  if (wid == 0) {
    int x = (lane < 16) ? wsum[lane] : 0;
    x = wave_incl_scan(x, lane);
    if (lane < 16) wsum[lane] = x;
  }
  __syncthreads();
  int off = (wid > 0 ? wsum[wid - 1] : 0) + (ws - p3) + chunk_off[blockIdx.x];
  if (base + 0 < n) row_ptr[base + 1] = off + p0;
  if (base + 1 < n) row_ptr[base + 2] = off + p1;
  if (base + 2 < n) row_ptr[base + 3] = off + p2;
  if (base + 3 < n) row_ptr[base + 4] = off + p3;
  if (blockIdx.x == 0 && tid == 0) row_ptr[0] = 0;
}

__global__ void copy_int_kernel(const int* __restrict__ a, int* __restrict__ b, int n) {
  int i = blockIdx.x * blockDim.x + threadIdx.x;
  if (i < n) b[i] = a[i];
}

__global__ void fill_csr_kernel(const void* __restrict__ ei, long long E,
                                int* __restrict__ cursor, int* __restrict__ csr_src,
                                const int* __restrict__ flag) {
  int is32 = *flag;
  long long e = (long long)blockIdx.x * blockDim.x + threadIdx.x;
  if (e >= E) return;
  int s = edge_at(ei, e, is32);
  int d = edge_at(ei, E + e, is32);
  int p = atomicAdd(&cursor[d], 1);
  csr_src[p] = s;
}

// ---------------- aggregation: one wave per destination node ----------------
// Lanes 0-31 handle even edges, lanes 32-63 odd edges; each half-wave reads a
// full 512B row as float4/lane. Edge indices+norms prefetched 64 at a time.
__global__ __launch_bounds__(256) void aggregate_kernel(
    const float* __restrict__ x, const float* __restrict__ nout,
    const int* __restrict__ row_ptr, const int* __restrict__ csr_src,
    float* __restrict__ agg, int n) {
  int wave = blockIdx.x * (blockDim.x >> 6) + (threadIdx.x >> 6);
  int lane = threadIdx.x & 63;
  if (wave >= n) return;
  int beg = row_ptr[wave], end = row_ptr[wave + 1];
  int deg = end - beg;
  int half = lane >> 5;       // which edge of the pair
  int sub = lane & 31;        // float4 slot within the row
  float ax = 0.f, ay = 0.f, az = 0.f, aw = 0.f;
  for (int j0 = 0; j0 < deg; j0 += 64) {
    int li = beg + j0 + lane;
    int idx = csr_src[li < end ? li : (end - 1)];
    float nrm = (li < end) ? nout[idx] : 0.f;
    int cnt = deg - j0; if (cnt > 64) cnt = 64;
    int cnt2 = (cnt + 1) >> 1;  // edge pairs this batch
#pragma unroll 4
    for (int t = 0; t < cnt2; ++t) {
      int e = 2 * t + half;                 // 0..63 always
      int s = __shfl(idx, e, 64);
      float sc = __shfl(nrm, e, 64);
      float4 v = *((const float4*)(x + (size_t)s * DF) + sub);
      ax += v.x * sc; ay += v.y * sc; az += v.z * sc; aw += v.w * sc;
    }
  }
  // combine even/odd halves: lane l (<32) += lane l+32
  ax += __shfl_down(ax, 32, 64);
  ay += __shfl_down(ay, 32, 64);
  az += __shfl_down(az, 32, 64);
  aw += __shfl_down(aw, 32, 64);
  if (half == 0) {
    float4 r; r.x = ax; r.y = ay; r.z = az; r.w = aw;
    *((float4*)(agg + (size_t)wave * DF) + sub) = r;
  }
}

// ---------------- row-wise transform: out[i,:] = din[i]*(agg[i,:]@W) + b -------
// 32-row x 128-col tile per group; each thread owns a 4x4 output block.
#define TR 32
__device__ __forceinline__ void fma4(float4& acc, float a, const float4& wv) {
  acc.x += a * wv.x; acc.y += a * wv.y; acc.z += a * wv.z; acc.w += a * wv.w;
}
__global__ __launch_bounds__(256) void transform_kernel(
    const float* __restrict__ agg, const float* __restrict__ nin,
    const float* __restrict__ W, const float* __restrict__ bias,
    float* __restrict__ out, int n) {
  __shared__ float Ws[DF * DF];   // 64 KiB, natural [k][j]
  __shared__ float As[TR][DF];    // 16 KiB
  for (int i = threadIdx.x; i < DF * DF / 4; i += 256)
    ((float4*)Ws)[i] = ((const float4*)W)[i];
  int c0 = (threadIdx.x & 31) * 4;   // 4 consecutive output cols
  int r0 = (threadIdx.x >> 5) * 4;   // 4 consecutive rows within tile
  float4 b4 = *((const float4*)(bias + c0));
  int ngroups = (n + TR - 1) / TR;
  for (int g = blockIdx.x; g < ngroups; g += gridDim.x) {
    int row0 = g * TR;
    __syncthreads();  // protects As reuse; also covers initial Ws load
    for (int i = threadIdx.x; i < TR * DF / 4; i += 256) {
      int rr = i >> 5;
      int row = row0 + rr;
      float4 v = {0.f, 0.f, 0.f, 0.f};
      if (row < n) v = ((const float4*)(agg + (size_t)row * DF))[i & 31];
      ((float4*)&As[0][0])[i] = v;
    }
    __syncthreads();
    float4 acc0 = {0,0,0,0}, acc1 = {0,0,0,0}, acc2 = {0,0,0,0}, acc3 = {0,0,0,0};
#pragma unroll 4
    for (int k = 0; k < DF; k += 4) {
      float4 a0 = *((const float4*)&As[r0 + 0][k]);
      float4 a1 = *((const float4*)&As[r0 + 1][k]);
      float4 a2 = *((const float4*)&As[r0 + 2][k]);
      float4 a3 = *((const float4*)&As[r0 + 3][k]);
      float4 w0 = *((const float4*)&Ws[(k + 0) * DF + c0]);
      float4 w1 = *((const float4*)&Ws[(k + 1) * DF + c0]);
      float4 w2 = *((const float4*)&Ws[(k + 2) * DF + c0]);
      float4 w3 = *((const float4*)&Ws[(k + 3) * DF + c0]);
      fma4(acc0, a0.x, w0); fma4(acc0, a0.y, w1); fma4(acc0, a0.z, w2); fma4(acc0, a0.w, w3);
      fma4(acc1, a1.x, w0); fma4(acc1, a1.y, w1); fma4(acc1, a1.z, w2); fma4(acc1, a1.w, w3);
      fma4(acc2, a2.x, w0); fma4(acc2, a2.y, w1); fma4(acc2, a2.z, w2); fma4(acc2, a2.w, w3);
      fma4(acc3, a3.x, w0); fma4(acc3, a3.y, w1); fma4(acc3, a3.z, w2); fma4(acc3, a3.w, w3);
    }
    int r = row0 + r0;
    if (r + 0 < n) { float s = nin[r + 0];
      float4 o; o.x = acc0.x * s + b4.x; o.y = acc0.y * s + b4.y; o.z = acc0.z * s + b4.z; o.w = acc0.w * s + b4.w;
      *((float4*)(out + (size_t)(r + 0) * DF + c0)) = o; }
    if (r + 1 < n) { float s = nin[r + 1];
      float4 o; o.x = acc1.x * s + b4.x; o.y = acc1.y * s + b4.y; o.z = acc1.z * s + b4.z; o.w = acc1.w * s + b4.w;
      *((float4*)(out + (size_t)(r + 1) * DF + c0)) = o; }
    if (r + 2 < n) { float s = nin[r + 2];
      float4 o; o.x = acc2.x * s + b4.x; o.y = acc2.y * s + b4.y; o.z = acc2.z * s + b4.z; o.w = acc2.w * s + b4.w;
      *((float4*)(out + (size_t)(r + 2) * DF + c0)) = o; }
    if (r + 3 < n) { float s = nin[r + 3];
      float4 o; o.x = acc3.x * s + b4.x; o.y = acc3.y * s + b4.y; o.z = acc3.z * s + b4.z; o.w = acc3.w * s + b4.w;
      *((float4*)(out + (size_t)(r + 3) * DF + c0)) = o; }
  }
}

extern "C" void kernel_launch(void* const* d_in, const int* in_sizes, int n_in,
                              void* d_out, int out_size, void* d_ws, size_t ws_size,
                              hipStream_t stream) {
  const float* in_feat = (const float*)d_in[0];
  const void*  ei      = d_in[1];
  const float* W1 = (const float*)d_in[2];
  const float* b1 = (const float*)d_in[3];
  const float* W2 = (const float*)d_in[4];
  const float* b2 = (const float*)d_in[5];
  float* out = (float*)d_out;

  const int N = in_sizes[0] / DF;
  const long long E = in_sizes[1] / 2;
  const int NB = (N + 4095) / 4096;

  size_t off = 0;
  auto take = [&](size_t nb) -> char* {
    char* p = (char*)d_ws + off;
    off += (nb + 255) & ~(size_t)255;
    return p;
  };
  float* agg    = (float*)take((size_t)N * DF * 4);  // 51.2 MB
  int* degs     = (int*)take((size_t)N * 4);
  int* degd     = (int*)take((size_t)N * 4);
  float* nout   = (float*)take((size_t)N * 4);
  float* nin    = (float*)take((size_t)N * 4);
  int* row_ptr  = (int*)take((size_t)(N + 1) * 4);
  int* cursor   = (int*)take((size_t)N * 4);
  int* partials = (int*)take((size_t)NB * 4);
  int* flag     = (int*)take(4);
  int* csr_src  = (int*)take((size_t)E * 4);         // 6.4 MB
  (void)ws_size; (void)n_in; (void)out_size;

  hipMemsetAsync(degs, 0, (size_t)N * 4, stream);
  hipMemsetAsync(degd, 0, (size_t)N * 4, stream);
  hipMemsetAsync(flag, 0, 4, stream);

  detect_dtype_kernel<<<8, 256, 0, stream>>>((const unsigned*)ei, (long long)in_sizes[1], flag);

  int eb = (int)((E + 255) / 256);
  int nb256 = (N + 255) / 256;

  degree_kernel<<<eb, 256, 0, stream>>>(ei, E, degs, degd, flag);
  norm_kernel<<<nb256, 256, 0, stream>>>(degs, degd, nout, nin, N);

  chunk_sum_kernel<<<NB, 1024, 0, stream>>>(degd, partials, N);
  scan_partials_kernel<<<1, 64, 0, stream>>>(partials, NB);
  scan_chunk_kernel<<<NB, 1024, 0, stream>>>(degd, partials, row_ptr, N);
  copy_int_kernel<<<nb256, 256, 0, stream>>>(row_ptr, cursor, N);
  fill_csr_kernel<<<eb, 256, 0, stream>>>(ei, E, cursor, csr_src, flag);

  int ab = (N + 3) / 4;  // 4 waves (nodes) per 256-thread block
  // conv1: in_feat -> agg -> h1 (stored in d_out)
  aggregate_kernel<<<ab, 256, 0, stream>>>(in_feat, nout, row_ptr, csr_src, agg, N);
  transform_kernel<<<512, 256, 0, stream>>>(agg, nin, W1, b1, out, N);
  // conv2: h1 (d_out) -> agg -> out (d_out, overwritten after reads complete)
  aggregate_kernel<<<ab, 256, 0, stream>>>(out, nout, row_ptr, csr_src, agg, N);
  transform_kernel<<<512, 256, 0, stream>>>(agg, nin, W2, b2, out, N);
}

// Round 4
// 549.829 us; speedup vs baseline: 1.5372x; 1.1442x over previous
//
#include <hip/hip_runtime.h>
#include <cstdint>
#include <cstddef>

#define DF 128

// ---------------- edge dtype handling (int32 vs int64 storage) ----------------
__device__ __forceinline__ int edge_at(const void* ei, long long idx, int is32) {
  return is32 ? ((const int*)ei)[idx] : (int)((const long long*)ei)[idx];
}

__global__ void detect_dtype_kernel(const unsigned* __restrict__ ei, long long nelem,
                                    int* __restrict__ flag) {
  long long half = nelem / 2;
  int t = threadIdx.x + blockIdx.x * blockDim.x;
  long long step = (half + 2047) / 2048;
  long long k = (long long)t * step;
  if (k < half && ei[2 * k + 1] != 0) atomicOr(flag, 1);
}

__device__ __forceinline__ unsigned xcc_id() {
  unsigned k;
  asm volatile("s_getreg_b32 %0, hwreg(HW_REG_XCC_ID)" : "=s"(k));
  return k & 7u;
}

// ---------------- pass A: per-XCD histograms + rank capture ----------------
// degs8/degd8 are [8][n]; atomics are workgroup-scope -> execute at the local
// XCD's TCC (L2) without the device-coherence write-through. Each line is only
// ever touched by one XCD (indexed by XCC_ID), so combining at that L2 is exact.
__global__ __launch_bounds__(256) void rank_kernel(
    const void* __restrict__ ei, long long E, int n,
    int* __restrict__ degs8, int* __restrict__ degd8,
    unsigned* __restrict__ rankp, const int* __restrict__ flag) {
  int is32 = *flag;
  long long e = (long long)blockIdx.x * blockDim.x + threadIdx.x;
  if (e >= E) return;
  unsigned k = xcc_id();
  int s = edge_at(ei, e, is32);
  int d = edge_at(ei, E + e, is32);
  int r = __hip_atomic_fetch_add(&degd8[(size_t)k * n + d], 1,
                                 __ATOMIC_RELAXED, __HIP_MEMORY_SCOPE_WORKGROUP);
  __hip_atomic_fetch_add(&degs8[(size_t)k * n + s], 1,
                         __ATOMIC_RELAXED, __HIP_MEMORY_SCOPE_WORKGROUP);
  rankp[e] = (k << 28) | (unsigned)r;
}

// ---------------- reduce 8 copies -> totals, norms; degd8 -> per-k prefix ----
__global__ void reduce_norm_kernel(int* __restrict__ degs8, int* __restrict__ degd8,
                                   float* __restrict__ nout, float* __restrict__ nin,
                                   int* __restrict__ degd, int n) {
  int i = blockIdx.x * blockDim.x + threadIdx.x;
  if (i >= n) return;
  int ss = 0;
#pragma unroll
  for (int k = 0; k < 8; ++k) ss += degs8[(size_t)k * n + i];
  int sd = 0;
#pragma unroll
  for (int k = 0; k < 8; ++k) {
    int t = degd8[(size_t)k * n + i];
    degd8[(size_t)k * n + i] = sd;   // exclusive prefix over XCD copies
    sd += t;
  }
  degd[i] = sd;
  nout[i] = rsqrtf((float)(ss > 1 ? ss : 1));
  nin[i]  = rsqrtf((float)(sd > 1 ? sd : 1));
}

// ---------------- exclusive scan (3-kernel, shfl-based) ----------------
__device__ __forceinline__ int wave_incl_scan(int v, int lane) {
#pragma unroll
  for (int off = 1; off < 64; off <<= 1) {
    int t = __shfl_up(v, off, 64);
    if (lane >= off) v += t;
  }
  return v;
}

__global__ void chunk_sum_kernel(const int* __restrict__ deg, int* __restrict__ partials, int n) {
  __shared__ int wsum[16];
  int tid = threadIdx.x, lane = tid & 63, wid = tid >> 6;
  int base = blockIdx.x * 4096 + tid * 4;
  int s = 0;
#pragma unroll
  for (int q = 0; q < 4; ++q) { int i = base + q; if (i < n) s += deg[i]; }
#pragma unroll
  for (int off = 32; off; off >>= 1) s += __shfl_down(s, off, 64);
  if (lane == 0) wsum[wid] = s;
  __syncthreads();
  if (tid == 0) {
    int t = 0;
#pragma unroll
    for (int w = 0; w < 16; ++w) t += wsum[w];
    partials[blockIdx.x] = t;
  }
}

__global__ void scan_partials_kernel(int* __restrict__ partials, int nb) {
  int lane = threadIdx.x;
  int carry = 0;
  for (int base = 0; base < nb; base += 64) {
    int i = base + lane;
    int v = (i < nb) ? partials[i] : 0;
    int s = wave_incl_scan(v, lane);
    if (i < nb) partials[i] = s - v + carry;  // exclusive + carry
    carry += __shfl(s, 63, 64);
  }
}

__global__ void scan_chunk_kernel(const int* __restrict__ deg, const int* __restrict__ chunk_off,
                                  int* __restrict__ row_ptr, int n) {
  __shared__ int wsum[16];
  int tid = threadIdx.x, lane = tid & 63, wid = tid >> 6;
  int base = blockIdx.x * 4096 + tid * 4;
  int v0 = (base + 0 < n) ? deg[base + 0] : 0;
  int v1 = (base + 1 < n) ? deg[base + 1] : 0;
  int v2 = (base + 2 < n) ? deg[base + 2] : 0;
  int v3 = (base + 3 < n) ? deg[base + 3] : 0;
  int p0 = v0, p1 = p0 + v1, p2 = p1 + v2, p3 = p2 + v3;
  int ws = wave_incl_scan(p3, lane);
  if (lane == 63) wsum[wid] = ws;
  __syncthreads();
  if (wid == 0) {
    int x = (lane < 16) ? wsum[lane] : 0;
    x = wave_incl_scan(x, lane);
    if (lane < 16) wsum[lane] = x;
  }
  __syncthreads();
  int off = (wid > 0 ? wsum[wid - 1] : 0) + (ws - p3) + chunk_off[blockIdx.x];
  if (base + 0 < n) row_ptr[base + 1] = off + p0;
  if (base + 1 < n) row_ptr[base + 2] = off + p1;
  if (base + 2 < n) row_ptr[base + 3] = off + p2;
  if (base + 3 < n) row_ptr[base + 4] = off + p3;
  if (blockIdx.x == 0 && tid == 0) row_ptr[0] = 0;
}

// ---------------- degd8[k][i] += row_ptr[i]  -> absolute per-(k,d) offsets ----
__global__ void add_rowptr_kernel(int* __restrict__ degd8, const int* __restrict__ row_ptr, int n) {
  int i = blockIdx.x * blockDim.x + threadIdx.x;
  if (i >= n) return;
  int rp = row_ptr[i];
#pragma unroll
  for (int k = 0; k < 8; ++k) degd8[(size_t)k * n + i] += rp;
}

// ---------------- pass B: atomic-free CSR fill ----------------
__global__ __launch_bounds__(256) void fill2_kernel(
    const void* __restrict__ ei, long long E, int n,
    const unsigned* __restrict__ rankp, const int* __restrict__ off8,
    int* __restrict__ csr_src, const int* __restrict__ flag) {
  int is32 = *flag;
  long long e = (long long)blockIdx.x * blockDim.x + threadIdx.x;
  if (e >= E) return;
  unsigned rp = rankp[e];
  unsigned k = rp >> 28;
  int r = (int)(rp & 0x0fffffffu);
  int s = edge_at(ei, e, is32);
  int d = edge_at(ei, E + e, is32);
  csr_src[off8[(size_t)k * n + d] + r] = s;
}

// ---------------- aggregation: one wave per destination node ----------------
__global__ __launch_bounds__(256) void aggregate_kernel(
    const float* __restrict__ x, const float* __restrict__ nout,
    const int* __restrict__ row_ptr, const int* __restrict__ csr_src,
    float* __restrict__ agg, int n) {
  int wave = blockIdx.x * (blockDim.x >> 6) + (threadIdx.x >> 6);
  int lane = threadIdx.x & 63;
  if (wave >= n) return;
  int beg = row_ptr[wave], end = row_ptr[wave + 1];
  int deg = end - beg;
  int half = lane >> 5;       // which edge of the pair
  int sub = lane & 31;        // float4 slot within the row
  float ax = 0.f, ay = 0.f, az = 0.f, aw = 0.f;
  for (int j0 = 0; j0 < deg; j0 += 64) {
    int li = beg + j0 + lane;
    int idx = csr_src[li < end ? li : (end - 1)];
    float nrm = (li < end) ? nout[idx] : 0.f;
    int cnt = deg - j0; if (cnt > 64) cnt = 64;
    int cnt2 = (cnt + 1) >> 1;  // edge pairs this batch
#pragma unroll 4
    for (int t = 0; t < cnt2; ++t) {
      int e = 2 * t + half;                 // 0..63 always
      int s = __shfl(idx, e, 64);
      float sc = __shfl(nrm, e, 64);
      float4 v = *((const float4*)(x + (size_t)s * DF) + sub);
      ax += v.x * sc; ay += v.y * sc; az += v.z * sc; aw += v.w * sc;
    }
  }
  ax += __shfl_down(ax, 32, 64);
  ay += __shfl_down(ay, 32, 64);
  az += __shfl_down(az, 32, 64);
  aw += __shfl_down(aw, 32, 64);
  if (half == 0) {
    float4 r; r.x = ax; r.y = ay; r.z = az; r.w = aw;
    *((float4*)(agg + (size_t)wave * DF) + sub) = r;
  }
}

// ---------------- row-wise transform: out[i,:] = din[i]*(agg[i,:]@W) + b -------
#define TR 32
__device__ __forceinline__ void fma4(float4& acc, float a, const float4& wv) {
  acc.x += a * wv.x; acc.y += a * wv.y; acc.z += a * wv.z; acc.w += a * wv.w;
}
__global__ __launch_bounds__(256) void transform_kernel(
    const float* __restrict__ agg, const float* __restrict__ nin,
    const float* __restrict__ W, const float* __restrict__ bias,
    float* __restrict__ out, int n) {
  __shared__ float Ws[DF * DF];   // 64 KiB, natural [k][j]
  __shared__ float As[TR][DF];    // 16 KiB
  for (int i = threadIdx.x; i < DF * DF / 4; i += 256)
    ((float4*)Ws)[i] = ((const float4*)W)[i];
  int c0 = (threadIdx.x & 31) * 4;   // 4 consecutive output cols
  int r0 = (threadIdx.x >> 5) * 4;   // 4 consecutive rows within tile
  float4 b4 = *((const float4*)(bias + c0));
  int ngroups = (n + TR - 1) / TR;
  for (int g = blockIdx.x; g < ngroups; g += gridDim.x) {
    int row0 = g * TR;
    __syncthreads();  // protects As reuse; also covers initial Ws load
    for (int i = threadIdx.x; i < TR * DF / 4; i += 256) {
      int rr = i >> 5;
      int row = row0 + rr;
      float4 v = {0.f, 0.f, 0.f, 0.f};
      if (row < n) v = ((const float4*)(agg + (size_t)row * DF))[i & 31];
      ((float4*)&As[0][0])[i] = v;
    }
    __syncthreads();
    float4 acc0 = {0,0,0,0}, acc1 = {0,0,0,0}, acc2 = {0,0,0,0}, acc3 = {0,0,0,0};
#pragma unroll 4
    for (int k = 0; k < DF; k += 4) {
      float4 a0 = *((const float4*)&As[r0 + 0][k]);
      float4 a1 = *((const float4*)&As[r0 + 1][k]);
      float4 a2 = *((const float4*)&As[r0 + 2][k]);
      float4 a3 = *((const float4*)&As[r0 + 3][k]);
      float4 w0 = *((const float4*)&Ws[(k + 0) * DF + c0]);
      float4 w1 = *((const float4*)&Ws[(k + 1) * DF + c0]);
      float4 w2 = *((const float4*)&Ws[(k + 2) * DF + c0]);
      float4 w3 = *((const float4*)&Ws[(k + 3) * DF + c0]);
      fma4(acc0, a0.x, w0); fma4(acc0, a0.y, w1); fma4(acc0, a0.z, w2); fma4(acc0, a0.w, w3);
      fma4(acc1, a1.x, w0); fma4(acc1, a1.y, w1); fma4(acc1, a1.z, w2); fma4(acc1, a1.w, w3);
      fma4(acc2, a2.x, w0); fma4(acc2, a2.y, w1); fma4(acc2, a2.z, w2); fma4(acc2, a2.w, w3);
      fma4(acc3, a3.x, w0); fma4(acc3, a3.y, w1); fma4(acc3, a3.z, w2); fma4(acc3, a3.w, w3);
    }
    int r = row0 + r0;
    if (r + 0 < n) { float s = nin[r + 0];
      float4 o; o.x = acc0.x * s + b4.x; o.y = acc0.y * s + b4.y; o.z = acc0.z * s + b4.z; o.w = acc0.w * s + b4.w;
      *((float4*)(out + (size_t)(r + 0) * DF + c0)) = o; }
    if (r + 1 < n) { float s = nin[r + 1];
      float4 o; o.x = acc1.x * s + b4.x; o.y = acc1.y * s + b4.y; o.z = acc1.z * s + b4.z; o.w = acc1.w * s + b4.w;
      *((float4*)(out + (size_t)(r + 1) * DF + c0)) = o; }
    if (r + 2 < n) { float s = nin[r + 2];
      float4 o; o.x = acc2.x * s + b4.x; o.y = acc2.y * s + b4.y; o.z = acc2.z * s + b4.z; o.w = acc2.w * s + b4.w;
      *((float4*)(out + (size_t)(r + 2) * DF + c0)) = o; }
    if (r + 3 < n) { float s = nin[r + 3];
      float4 o; o.x = acc3.x * s + b4.x; o.y = acc3.y * s + b4.y; o.z = acc3.z * s + b4.z; o.w = acc3.w * s + b4.w;
      *((float4*)(out + (size_t)(r + 3) * DF + c0)) = o; }
  }
}

extern "C" void kernel_launch(void* const* d_in, const int* in_sizes, int n_in,
                              void* d_out, int out_size, void* d_ws, size_t ws_size,
                              hipStream_t stream) {
  const float* in_feat = (const float*)d_in[0];
  const void*  ei      = d_in[1];
  const float* W1 = (const float*)d_in[2];
  const float* b1 = (const float*)d_in[3];
  const float* W2 = (const float*)d_in[4];
  const float* b2 = (const float*)d_in[5];
  float* out = (float*)d_out;

  const int N = in_sizes[0] / DF;
  const long long E = in_sizes[1] / 2;
  const int NB = (N + 4095) / 4096;

  size_t off = 0;
  auto take = [&](size_t nb) -> char* {
    char* p = (char*)d_ws + off;
    off += (nb + 255) & ~(size_t)255;
    return p;
  };
  float* agg     = (float*)take((size_t)N * DF * 4);   // 51.2 MB
  int* degs8     = (int*)take((size_t)8 * N * 4);      // 3.2 MB
  int* degd8     = (int*)take((size_t)8 * N * 4);      // 3.2 MB (becomes off8)
  int* degd      = (int*)take((size_t)N * 4);
  float* nout    = (float*)take((size_t)N * 4);
  float* nin     = (float*)take((size_t)N * 4);
  int* row_ptr   = (int*)take((size_t)(N + 1) * 4);
  int* partials  = (int*)take((size_t)NB * 4);
  int* flag      = (int*)take(4);
  unsigned* rankp = (unsigned*)take((size_t)E * 4);    // 6.4 MB
  int* csr_src   = (int*)take((size_t)E * 4);          // 6.4 MB
  (void)ws_size; (void)n_in; (void)out_size;

  hipMemsetAsync(degs8, 0, (size_t)8 * N * 4, stream);
  hipMemsetAsync(degd8, 0, (size_t)8 * N * 4, stream);
  hipMemsetAsync(flag, 0, 4, stream);

  detect_dtype_kernel<<<8, 256, 0, stream>>>((const unsigned*)ei, (long long)in_sizes[1], flag);

  int eb = (int)((E + 255) / 256);
  int nb256 = (N + 255) / 256;

  rank_kernel<<<eb, 256, 0, stream>>>(ei, E, N, degs8, degd8, rankp, flag);
  reduce_norm_kernel<<<nb256, 256, 0, stream>>>(degs8, degd8, nout, nin, degd, N);

  chunk_sum_kernel<<<NB, 1024, 0, stream>>>(degd, partials, N);
  scan_partials_kernel<<<1, 64, 0, stream>>>(partials, NB);
  scan_chunk_kernel<<<NB, 1024, 0, stream>>>(degd, partials, row_ptr, N);
  add_rowptr_kernel<<<nb256, 256, 0, stream>>>(degd8, row_ptr, N);

  fill2_kernel<<<eb, 256, 0, stream>>>(ei, E, N, rankp, degd8, csr_src, flag);

  int ab = (N + 3) / 4;  // 4 waves (nodes) per 256-thread block
  // conv1: in_feat -> agg -> h1 (stored in d_out)
  aggregate_kernel<<<ab, 256, 0, stream>>>(in_feat, nout, row_ptr, csr_src, agg, N);
  transform_kernel<<<512, 256, 0, stream>>>(agg, nin, W1, b1, out, N);
  // conv2: h1 (d_out) -> agg -> out (d_out, overwritten after reads complete)
  aggregate_kernel<<<ab, 256, 0, stream>>>(out, nout, row_ptr, csr_src, agg, N);
  transform_kernel<<<512, 256, 0, stream>>>(agg, nin, W2, b2, out, N);
}

// Round 5
// 433.395 us; speedup vs baseline: 1.9502x; 1.2687x over previous
//
#include <hip/hip_runtime.h>
#include <cstdint>
#include <cstddef>

#define DF 128
#define PB 512        // partition blocks
#define RSH 8         // bucket = node >> RSH
#define RNG 256       // nodes per bucket
#define CAP 6144      // LDS staging capacity (edges) per bucket

// ---------------- edge dtype handling (int32 vs int64 storage) ----------------
__device__ __forceinline__ int edge_at(const void* ei, long long idx, int is32) {
  return is32 ? ((const int*)ei)[idx] : (int)((const long long*)ei)[idx];
}

__global__ void detect_dtype_kernel(const unsigned* __restrict__ ei, long long nelem,
                                    int* __restrict__ flag) {
  long long half = nelem / 2;
  int t = threadIdx.x + blockIdx.x * blockDim.x;
  long long step = (half + 2047) / 2048;
  long long k = (long long)t * step;
  if (k < half && ei[2 * k + 1] != 0) atomicOr(flag, 1);
}

// ---------------- L1: per-block bucket histograms (LDS atomics only) ----------
__global__ __launch_bounds__(256) void part_count_kernel(
    const void* __restrict__ ei, long long E, int nbuck, int chunk,
    int* __restrict__ H, const int* __restrict__ flag) {
  __shared__ int hd[512], hs[512];
  int is32 = *flag;
  int blk = blockIdx.x, t = threadIdx.x;
  for (int i = t; i < 512; i += 256) { hd[i] = 0; hs[i] = 0; }
  __syncthreads();
  long long lo = (long long)blk * chunk;
  long long hi = lo + chunk; if (hi > E) hi = E;
  for (long long e = lo + t; e < hi; e += 256) {
    int s = edge_at(ei, e, is32);
    int d = edge_at(ei, E + e, is32);
    atomicAdd(&hs[s >> RSH], 1);
    atomicAdd(&hd[d >> RSH], 1);
  }
  __syncthreads();
  for (int b = t; b < nbuck; b += 256) {
    H[(size_t)b * PB + blk] = hd[b];
    H[((size_t)nbuck + b) * PB + blk] = hs[b];
  }
}

// ---------------- exclusive scan (3-kernel, shfl-based) ----------------
__device__ __forceinline__ int wave_incl_scan(int v, int lane) {
#pragma unroll
  for (int off = 1; off < 64; off <<= 1) {
    int t = __shfl_up(v, off, 64);
    if (lane >= off) v += t;
  }
  return v;
}

__global__ void chunk_sum_kernel(const int* __restrict__ deg, int* __restrict__ partials, int n) {
  __shared__ int wsum[16];
  int tid = threadIdx.x, lane = tid & 63, wid = tid >> 6;
  int base = blockIdx.x * 4096 + tid * 4;
  int s = 0;
#pragma unroll
  for (int q = 0; q < 4; ++q) { int i = base + q; if (i < n) s += deg[i]; }
#pragma unroll
  for (int off = 32; off; off >>= 1) s += __shfl_down(s, off, 64);
  if (lane == 0) wsum[wid] = s;
  __syncthreads();
  if (tid == 0) {
    int t = 0;
#pragma unroll
    for (int w = 0; w < 16; ++w) t += wsum[w];
    partials[blockIdx.x] = t;
  }
}

__global__ void scan_partials_kernel(int* __restrict__ partials, int nb) {
  int lane = threadIdx.x;
  int carry = 0;
  for (int base = 0; base < nb; base += 64) {
    int i = base + lane;
    int v = (i < nb) ? partials[i] : 0;
    int s = wave_incl_scan(v, lane);
    if (i < nb) partials[i] = s - v + carry;  // exclusive + carry
    carry += __shfl(s, 63, 64);
  }
}

__global__ void scan_chunk_kernel(const int* __restrict__ deg, const int* __restrict__ chunk_off,
                                  int* __restrict__ row_ptr, int n) {
  __shared__ int wsum[16];
  int tid = threadIdx.x, lane = tid & 63, wid = tid >> 6;
  int base = blockIdx.x * 4096 + tid * 4;
  int v0 = (base + 0 < n) ? deg[base + 0] : 0;
  int v1 = (base + 1 < n) ? deg[base + 1] : 0;
  int v2 = (base + 2 < n) ? deg[base + 2] : 0;
  int v3 = (base + 3 < n) ? deg[base + 3] : 0;
  int p0 = v0, p1 = p0 + v1, p2 = p1 + v2, p3 = p2 + v3;
  int ws = wave_incl_scan(p3, lane);
  if (lane == 63) wsum[wid] = ws;
  __syncthreads();
  if (wid == 0) {
    int x = (lane < 16) ? wsum[lane] : 0;
    x = wave_incl_scan(x, lane);
    if (lane < 16) wsum[lane] = x;
  }
  __syncthreads();
  int off = (wid > 0 ? wsum[wid - 1] : 0) + (ws - p3) + chunk_off[blockIdx.x];
  if (base + 0 < n) row_ptr[base + 1] = off + p0;
  if (base + 1 < n) row_ptr[base + 2] = off + p1;
  if (base + 2 < n) row_ptr[base + 3] = off + p2;
  if (base + 3 < n) row_ptr[base + 4] = off + p3;
  if (blockIdx.x == 0 && tid == 0) row_ptr[0] = 0;
}

// ---------------- L1b: scatter into bucket segments (LDS ranks, plain stores) --
__global__ __launch_bounds__(256) void part_scatter_kernel(
    const void* __restrict__ ei, long long E, int nbuck, int chunk,
    const int* __restrict__ Hs, unsigned* __restrict__ pack_d,
    unsigned char* __restrict__ src_loc, const int* __restrict__ flag) {
  __shared__ int hd[512], hs[512], bd[512], bs[512];
  int is32 = *flag;
  int blk = blockIdx.x, t = threadIdx.x;
  for (int i = t; i < 512; i += 256) { hd[i] = 0; hs[i] = 0; }
  __syncthreads();
  for (int b = t; b < nbuck; b += 256) {
    bd[b] = Hs[(size_t)b * PB + blk];
    bs[b] = Hs[((size_t)nbuck + b) * PB + blk] - (int)E;
  }
  __syncthreads();
  long long lo = (long long)blk * chunk;
  long long hi = lo + chunk; if (hi > E) hi = E;
  for (long long e = lo + t; e < hi; e += 256) {
    int s = edge_at(ei, e, is32);
    int d = edge_at(ei, E + e, is32);
    int kb = d >> RSH;
    int rd = atomicAdd(&hd[kb], 1);
    pack_d[bd[kb] + rd] = ((unsigned)(d & (RNG - 1)) << 24) | (unsigned)s;
    int ks = s >> RSH;
    int rs = atomicAdd(&hs[ks], 1);
    src_loc[bs[ks] + rs] = (unsigned char)(s & (RNG - 1));
  }
}

// ---------------- L2: per-bucket CSR build (row_ptr, nin, csr_src) -------------
__global__ __launch_bounds__(256) void bucket_build_kernel(
    const unsigned* __restrict__ pack_d, const int* __restrict__ Hs,
    long long E, int n, int* __restrict__ row_ptr, float* __restrict__ nin,
    int* __restrict__ csr_src) {
  __shared__ unsigned stage[CAP];
  __shared__ int cnt[RNG], cur[RNG], woff[4];
  int b = blockIdx.x, t = threadIdx.x;
  int lane = t & 63, wv = t >> 6;
  int start = Hs[(size_t)b * PB];
  int end = Hs[(size_t)(b + 1) * PB];
  int len = end - start;
  cnt[t] = 0;
  __syncthreads();
  bool fits = (len <= CAP);
  for (int i = t; i < len; i += 256) {
    unsigned p = pack_d[start + i];
    if (fits) stage[i] = p;
    atomicAdd(&cnt[p >> 24], 1);
  }
  __syncthreads();
  int dreg = cnt[t];
  int isc = wave_incl_scan(dreg, lane);
  if (lane == 63) woff[wv] = isc;
  __syncthreads();
  int add = 0;
#pragma unroll
  for (int w = 0; w < 4; ++w) if (w < wv) add += woff[w];
  int excl = isc - dreg + add;
  int nd = b * RNG + t;
  if (nd < n) {
    row_ptr[nd] = start + excl;
    nin[nd] = rsqrtf((float)(dreg > 1 ? dreg : 1));
  }
  if (b == (int)gridDim.x - 1 && t == 0) row_ptr[n] = (int)E;
  cur[t] = excl;
  __syncthreads();
  for (int i = t; i < len; i += 256) {
    unsigned p = fits ? stage[i] : pack_d[start + i];
    int dl = (int)(p >> 24);
    int r = atomicAdd(&cur[dl], 1);
    csr_src[start + r] = (int)(p & 0xFFFFFFu);
  }
}

// ---------------- L2s: per-bucket src-degree count -> nout ---------------------
__global__ __launch_bounds__(256) void src_deg_kernel(
    const unsigned char* __restrict__ src_loc, const int* __restrict__ Hs,
    int nbuck, long long E, int n, float* __restrict__ nout) {
  __shared__ int cnt[RNG];
  int b = blockIdx.x, t = threadIdx.x;
  int start = Hs[(size_t)(nbuck + b) * PB] - (int)E;
  int end = Hs[(size_t)(nbuck + b + 1) * PB] - (int)E;
  cnt[t] = 0;
  __syncthreads();
  for (int i = start + t; i < end; i += 256) atomicAdd(&cnt[src_loc[i]], 1);
  __syncthreads();
  int nd = b * RNG + t;
  if (nd < n) nout[nd] = rsqrtf((float)(cnt[t] > 1 ? cnt[t] : 1));
}

// ---------------- aggregation: one wave per destination node ----------------
__global__ __launch_bounds__(256) void aggregate_kernel(
    const float* __restrict__ x, const float* __restrict__ nout,
    const int* __restrict__ row_ptr, const int* __restrict__ csr_src,
    float* __restrict__ agg, int n) {
  int wave = blockIdx.x * (blockDim.x >> 6) + (threadIdx.x >> 6);
  int lane = threadIdx.x & 63;
  if (wave >= n) return;
  int beg = row_ptr[wave], end = row_ptr[wave + 1];
  int deg = end - beg;
  int half = lane >> 5;       // which edge of the pair
  int sub = lane & 31;        // float4 slot within the row
  float ax = 0.f, ay = 0.f, az = 0.f, aw = 0.f;
  for (int j0 = 0; j0 < deg; j0 += 64) {
    int li = beg + j0 + lane;
    int idx = csr_src[li < end ? li : (end - 1)];
    float nrm = (li < end) ? nout[idx] : 0.f;
    int cnt = deg - j0; if (cnt > 64) cnt = 64;
    int cnt2 = (cnt + 1) >> 1;  // edge pairs this batch
#pragma unroll 4
    for (int t = 0; t < cnt2; ++t) {
      int e = 2 * t + half;                 // 0..63 always
      int s = __shfl(idx, e, 64);
      float sc = __shfl(nrm, e, 64);
      float4 v = *((const float4*)(x + (size_t)s * DF) + sub);
      ax += v.x * sc; ay += v.y * sc; az += v.z * sc; aw += v.w * sc;
    }
  }
  ax += __shfl_down(ax, 32, 64);
  ay += __shfl_down(ay, 32, 64);
  az += __shfl_down(az, 32, 64);
  aw += __shfl_down(aw, 32, 64);
  if (half == 0) {
    float4 r; r.x = ax; r.y = ay; r.z = az; r.w = aw;
    *((float4*)(agg + (size_t)wave * DF) + sub) = r;
  }
}

// ---------------- row-wise transform: out[i,:] = din[i]*(agg[i,:]@W) + b -------
#define TR 32
__device__ __forceinline__ void fma4(float4& acc, float a, const float4& wv) {
  acc.x += a * wv.x; acc.y += a * wv.y; acc.z += a * wv.z; acc.w += a * wv.w;
}
__global__ __launch_bounds__(256) void transform_kernel(
    const float* __restrict__ agg, const float* __restrict__ nin,
    const float* __restrict__ W, const float* __restrict__ bias,
    float* __restrict__ out, int n) {
  __shared__ float Ws[DF * DF];   // 64 KiB, natural [k][j]
  __shared__ float As[TR][DF];    // 16 KiB
  for (int i = threadIdx.x; i < DF * DF / 4; i += 256)
    ((float4*)Ws)[i] = ((const float4*)W)[i];
  int c0 = (threadIdx.x & 31) * 4;   // 4 consecutive output cols
  int r0 = (threadIdx.x >> 5) * 4;   // 4 consecutive rows within tile
  float4 b4 = *((const float4*)(bias + c0));
  int ngroups = (n + TR - 1) / TR;
  for (int g = blockIdx.x; g < ngroups; g += gridDim.x) {
    int row0 = g * TR;
    __syncthreads();  // protects As reuse; also covers initial Ws load
    for (int i = threadIdx.x; i < TR * DF / 4; i += 256) {
      int rr = i >> 5;
      int row = row0 + rr;
      float4 v = {0.f, 0.f, 0.f, 0.f};
      if (row < n) v = ((const float4*)(agg + (size_t)row * DF))[i & 31];
      ((float4*)&As[0][0])[i] = v;
    }
    __syncthreads();
    float4 acc0 = {0,0,0,0}, acc1 = {0,0,0,0}, acc2 = {0,0,0,0}, acc3 = {0,0,0,0};
#pragma unroll 4
    for (int k = 0; k < DF; k += 4) {
      float4 a0 = *((const float4*)&As[r0 + 0][k]);
      float4 a1 = *((const float4*)&As[r0 + 1][k]);
      float4 a2 = *((const float4*)&As[r0 + 2][k]);
      float4 a3 = *((const float4*)&As[r0 + 3][k]);
      float4 w0 = *((const float4*)&Ws[(k + 0) * DF + c0]);
      float4 w1 = *((const float4*)&Ws[(k + 1) * DF + c0]);
      float4 w2 = *((const float4*)&Ws[(k + 2) * DF + c0]);
      float4 w3 = *((const float4*)&Ws[(k + 3) * DF + c0]);
      fma4(acc0, a0.x, w0); fma4(acc0, a0.y, w1); fma4(acc0, a0.z, w2); fma4(acc0, a0.w, w3);
      fma4(acc1, a1.x, w0); fma4(acc1, a1.y, w1); fma4(acc1, a1.z, w2); fma4(acc1, a1.w, w3);
      fma4(acc2, a2.x, w0); fma4(acc2, a2.y, w1); fma4(acc2, a2.z, w2); fma4(acc2, a2.w, w3);
      fma4(acc3, a3.x, w0); fma4(acc3, a3.y, w1); fma4(acc3, a3.z, w2); fma4(acc3, a3.w, w3);
    }
    int r = row0 + r0;
    if (r + 0 < n) { float s = nin[r + 0];
      float4 o; o.x = acc0.x * s + b4.x; o.y = acc0.y * s + b4.y; o.z = acc0.z * s + b4.z; o.w = acc0.w * s + b4.w;
      *((float4*)(out + (size_t)(r + 0) * DF + c0)) = o; }
    if (r + 1 < n) { float s = nin[r + 1];
      float4 o; o.x = acc1.x * s + b4.x; o.y = acc1.y * s + b4.y; o.z = acc1.z * s + b4.z; o.w = acc1.w * s + b4.w;
      *((float4*)(out + (size_t)(r + 1) * DF + c0)) = o; }
    if (r + 2 < n) { float s = nin[r + 2];
      float4 o; o.x = acc2.x * s + b4.x; o.y = acc2.y * s + b4.y; o.z = acc2.z * s + b4.z; o.w = acc2.w * s + b4.w;
      *((float4*)(out + (size_t)(r + 2) * DF + c0)) = o; }
    if (r + 3 < n) { float s = nin[r + 3];
      float4 o; o.x = acc3.x * s + b4.x; o.y = acc3.y * s + b4.y; o.z = acc3.z * s + b4.z; o.w = acc3.w * s + b4.w;
      *((float4*)(out + (size_t)(r + 3) * DF + c0)) = o; }
  }
}

extern "C" void kernel_launch(void* const* d_in, const int* in_sizes, int n_in,
                              void* d_out, int out_size, void* d_ws, size_t ws_size,
                              hipStream_t stream) {
  const float* in_feat = (const float*)d_in[0];
  const void*  ei      = d_in[1];
  const float* W1 = (const float*)d_in[2];
  const float* b1 = (const float*)d_in[3];
  const float* W2 = (const float*)d_in[4];
  const float* b2 = (const float*)d_in[5];
  float* out = (float*)d_out;

  const int N = in_sizes[0] / DF;
  const long long E = in_sizes[1] / 2;
  const int nbuck = (N + RNG - 1) >> RSH;          // 391 for N=100K (must be <=512)
  const int M = 2 * nbuck * PB;                    // histogram array length
  const int NB2 = (M + 4095) / 4096;               // scan chunks
  const int chunk = (int)((E + PB - 1) / PB);      // edges per partition block

  size_t off = 0;
  auto take = [&](size_t nb) -> char* {
    char* p = (char*)d_ws + off;
    off += (nb + 255) & ~(size_t)255;
    return p;
  };
  float* agg      = (float*)take((size_t)N * DF * 4);   // 51.2 MB
  int* H          = (int*)take((size_t)M * 4);          // 1.6 MB
  int* Hs         = (int*)take((size_t)(M + 1) * 4);    // 1.6 MB
  int* partials   = (int*)take((size_t)NB2 * 4);
  int* row_ptr    = (int*)take((size_t)(N + 1) * 4);
  float* nout     = (float*)take((size_t)N * 4);
  float* nin      = (float*)take((size_t)N * 4);
  int* flag       = (int*)take(4);
  unsigned* pack_d = (unsigned*)take((size_t)E * 4);    // 6.4 MB
  unsigned char* src_loc = (unsigned char*)take((size_t)E); // 1.6 MB
  int* csr_src    = (int*)take((size_t)E * 4);          // 6.4 MB
  (void)ws_size; (void)n_in; (void)out_size;

  hipMemsetAsync(flag, 0, 4, stream);
  detect_dtype_kernel<<<8, 256, 0, stream>>>((const unsigned*)ei, (long long)in_sizes[1], flag);

  part_count_kernel<<<PB, 256, 0, stream>>>(ei, E, nbuck, chunk, H, flag);
  chunk_sum_kernel<<<NB2, 1024, 0, stream>>>(H, partials, M);
  scan_partials_kernel<<<1, 64, 0, stream>>>(partials, NB2);
  scan_chunk_kernel<<<NB2, 1024, 0, stream>>>(H, partials, Hs, M);
  part_scatter_kernel<<<PB, 256, 0, stream>>>(ei, E, nbuck, chunk, Hs, pack_d, src_loc, flag);
  bucket_build_kernel<<<nbuck, 256, 0, stream>>>(pack_d, Hs, E, N, row_ptr, nin, csr_src);
  src_deg_kernel<<<nbuck, 256, 0, stream>>>(src_loc, Hs, nbuck, E, N, nout);

  int ab = (N + 3) / 4;  // 4 waves (nodes) per 256-thread block
  // conv1: in_feat -> agg -> h1 (stored in d_out)
  aggregate_kernel<<<ab, 256, 0, stream>>>(in_feat, nout, row_ptr, csr_src, agg, N);
  transform_kernel<<<512, 256, 0, stream>>>(agg, nin, W1, b1, out, N);
  // conv2: h1 (d_out) -> agg -> out (d_out, overwritten after reads complete)
  aggregate_kernel<<<ab, 256, 0, stream>>>(out, nout, row_ptr, csr_src, agg, N);
  transform_kernel<<<512, 256, 0, stream>>>(agg, nin, W2, b2, out, N);
}

// Round 6
// 427.847 us; speedup vs baseline: 1.9755x; 1.0130x over previous
//
#include <hip/hip_runtime.h>
#include <cstdint>
#include <cstddef>

#define DF 128
#define PB 512        // partition blocks
#define RSH 8         // bucket = node >> RSH
#define RNG 256       // nodes per bucket
#define CAP 6144      // LDS staging capacity (edges) per bucket

// ---------------- edge dtype handling (int32 vs int64 storage) ----------------
__device__ __forceinline__ int edge_at(const void* ei, long long idx, int is32) {
  return is32 ? ((const int*)ei)[idx] : (int)((const long long*)ei)[idx];
}

__global__ void detect_dtype_kernel(const unsigned* __restrict__ ei, long long nelem,
                                    int* __restrict__ flag) {
  long long half = nelem / 2;
  int t = threadIdx.x + blockIdx.x * blockDim.x;
  long long step = (half + 2047) / 2048;
  long long k = (long long)t * step;
  if (k < half && ei[2 * k + 1] != 0) atomicOr(flag, 1);
}

// ---------------- L1: per-block bucket histograms (LDS atomics only) ----------
__global__ __launch_bounds__(256) void part_count_kernel(
    const void* __restrict__ ei, long long E, int nbuck, int chunk,
    int* __restrict__ H, const int* __restrict__ flag) {
  __shared__ int hd[512], hs[512];
  int is32 = *flag;
  int blk = blockIdx.x, t = threadIdx.x;
  for (int i = t; i < 512; i += 256) { hd[i] = 0; hs[i] = 0; }
  __syncthreads();
  long long lo = (long long)blk * chunk;
  long long hi = lo + chunk; if (hi > E) hi = E;
  for (long long e = lo + t; e < hi; e += 256) {
    int s = edge_at(ei, e, is32);
    int d = edge_at(ei, E + e, is32);
    atomicAdd(&hs[s >> RSH], 1);
    atomicAdd(&hd[d >> RSH], 1);
  }
  __syncthreads();
  for (int b = t; b < nbuck; b += 256) {
    H[(size_t)b * PB + blk] = hd[b];
    H[((size_t)nbuck + b) * PB + blk] = hs[b];
  }
}

// ---------------- exclusive scan (3-kernel, shfl-based) ----------------
__device__ __forceinline__ int wave_incl_scan(int v, int lane) {
#pragma unroll
  for (int off = 1; off < 64; off <<= 1) {
    int t = __shfl_up(v, off, 64);
    if (lane >= off) v += t;
  }
  return v;
}

__global__ void chunk_sum_kernel(const int* __restrict__ deg, int* __restrict__ partials, int n) {
  __shared__ int wsum[16];
  int tid = threadIdx.x, lane = tid & 63, wid = tid >> 6;
  int base = blockIdx.x * 4096 + tid * 4;
  int s = 0;
#pragma unroll
  for (int q = 0; q < 4; ++q) { int i = base + q; if (i < n) s += deg[i]; }
#pragma unroll
  for (int off = 32; off; off >>= 1) s += __shfl_down(s, off, 64);
  if (lane == 0) wsum[wid] = s;
  __syncthreads();
  if (tid == 0) {
    int t = 0;
#pragma unroll
    for (int w = 0; w < 16; ++w) t += wsum[w];
    partials[blockIdx.x] = t;
  }
}

__global__ void scan_partials_kernel(int* __restrict__ partials, int nb) {
  int lane = threadIdx.x;
  int carry = 0;
  for (int base = 0; base < nb; base += 64) {
    int i = base + lane;
    int v = (i < nb) ? partials[i] : 0;
    int s = wave_incl_scan(v, lane);
    if (i < nb) partials[i] = s - v + carry;  // exclusive + carry
    carry += __shfl(s, 63, 64);
  }
}

__global__ void scan_chunk_kernel(const int* __restrict__ deg, const int* __restrict__ chunk_off,
                                  int* __restrict__ row_ptr, int n) {
  __shared__ int wsum[16];
  int tid = threadIdx.x, lane = tid & 63, wid = tid >> 6;
  int base = blockIdx.x * 4096 + tid * 4;
  int v0 = (base + 0 < n) ? deg[base + 0] : 0;
  int v1 = (base + 1 < n) ? deg[base + 1] : 0;
  int v2 = (base + 2 < n) ? deg[base + 2] : 0;
  int v3 = (base + 3 < n) ? deg[base + 3] : 0;
  int p0 = v0, p1 = p0 + v1, p2 = p1 + v2, p3 = p2 + v3;
  int ws = wave_incl_scan(p3, lane);
  if (lane == 63) wsum[wid] = ws;
  __syncthreads();
  if (wid == 0) {
    int x = (lane < 16) ? wsum[lane] : 0;
    x = wave_incl_scan(x, lane);
    if (lane < 16) wsum[lane] = x;
  }
  __syncthreads();
  int off = (wid > 0 ? wsum[wid - 1] : 0) + (ws - p3) + chunk_off[blockIdx.x];
  if (base + 0 < n) row_ptr[base + 1] = off + p0;
  if (base + 1 < n) row_ptr[base + 2] = off + p1;
  if (base + 2 < n) row_ptr[base + 3] = off + p2;
  if (base + 3 < n) row_ptr[base + 4] = off + p3;
  if (blockIdx.x == 0 && tid == 0) row_ptr[0] = 0;
}

// ---------------- L1b: scatter into bucket segments (LDS ranks, plain stores) --
__global__ __launch_bounds__(256) void part_scatter_kernel(
    const void* __restrict__ ei, long long E, int nbuck, int chunk,
    const int* __restrict__ Hs, unsigned* __restrict__ pack_d,
    unsigned char* __restrict__ src_loc, const int* __restrict__ flag) {
  __shared__ int hd[512], hs[512], bd[512], bs[512];
  int is32 = *flag;
  int blk = blockIdx.x, t = threadIdx.x;
  for (int i = t; i < 512; i += 256) { hd[i] = 0; hs[i] = 0; }
  __syncthreads();
  for (int b = t; b < nbuck; b += 256) {
    bd[b] = Hs[(size_t)b * PB + blk];
    bs[b] = Hs[((size_t)nbuck + b) * PB + blk] - (int)E;
  }
  __syncthreads();
  long long lo = (long long)blk * chunk;
  long long hi = lo + chunk; if (hi > E) hi = E;
  for (long long e = lo + t; e < hi; e += 256) {
    int s = edge_at(ei, e, is32);
    int d = edge_at(ei, E + e, is32);
    int kb = d >> RSH;
    int rd = atomicAdd(&hd[kb], 1);
    pack_d[bd[kb] + rd] = ((unsigned)(d & (RNG - 1)) << 24) | (unsigned)s;
    int ks = s >> RSH;
    int rs = atomicAdd(&hs[ks], 1);
    src_loc[bs[ks] + rs] = (unsigned char)(s & (RNG - 1));
  }
}

// ---------------- L2: per-bucket CSR build (row_ptr, nin, csr_src) -------------
__global__ __launch_bounds__(256) void bucket_build_kernel(
    const unsigned* __restrict__ pack_d, const int* __restrict__ Hs,
    long long E, int n, int* __restrict__ row_ptr, float* __restrict__ nin,
    int* __restrict__ csr_src) {
  __shared__ unsigned stage[CAP];
  __shared__ int cnt[RNG], cur[RNG], woff[4];
  int b = blockIdx.x, t = threadIdx.x;
  int lane = t & 63, wv = t >> 6;
  int start = Hs[(size_t)b * PB];
  int end = Hs[(size_t)(b + 1) * PB];
  int len = end - start;
  cnt[t] = 0;
  __syncthreads();
  bool fits = (len <= CAP);
  for (int i = t; i < len; i += 256) {
    unsigned p = pack_d[start + i];
    if (fits) stage[i] = p;
    atomicAdd(&cnt[p >> 24], 1);
  }
  __syncthreads();
  int dreg = cnt[t];
  int isc = wave_incl_scan(dreg, lane);
  if (lane == 63) woff[wv] = isc;
  __syncthreads();
  int add = 0;
#pragma unroll
  for (int w = 0; w < 4; ++w) if (w < wv) add += woff[w];
  int excl = isc - dreg + add;
  int nd = b * RNG + t;
  if (nd < n) {
    row_ptr[nd] = start + excl;
    nin[nd] = rsqrtf((float)(dreg > 1 ? dreg : 1));
  }
  if (b == (int)gridDim.x - 1 && t == 0) row_ptr[n] = (int)E;
  cur[t] = excl;
  __syncthreads();
  for (int i = t; i < len; i += 256) {
    unsigned p = fits ? stage[i] : pack_d[start + i];
    int dl = (int)(p >> 24);
    int r = atomicAdd(&cur[dl], 1);
    csr_src[start + r] = (int)(p & 0xFFFFFFu);
  }
}

// ---------------- L2s: per-bucket src-degree count -> nout ---------------------
__global__ __launch_bounds__(256) void src_deg_kernel(
    const unsigned char* __restrict__ src_loc, const int* __restrict__ Hs,
    int nbuck, long long E, int n, float* __restrict__ nout) {
  __shared__ int cnt[RNG];
  int b = blockIdx.x, t = threadIdx.x;
  int start = Hs[(size_t)(nbuck + b) * PB] - (int)E;
  int end = Hs[(size_t)(nbuck + b + 1) * PB] - (int)E;
  cnt[t] = 0;
  __syncthreads();
  for (int i = start + t; i < end; i += 256) atomicAdd(&cnt[src_loc[i]], 1);
  __syncthreads();
  int nd = b * RNG + t;
  if (nd < n) nout[nd] = rsqrtf((float)(cnt[t] > 1 ? cnt[t] : 1));
}

// ---------------- aggregation: one wave per destination node ----------------
// 8 independent row-loads in flight per wave (2 edges/wave-instr via half-waves,
// float4/lane = 512B row). nout==null -> input is pre-scaled, mask only.
__global__ __launch_bounds__(256) void aggregate_kernel(
    const float* __restrict__ x, const float* __restrict__ nout,
    const int* __restrict__ row_ptr, const int* __restrict__ csr_src,
    float* __restrict__ agg, int n) {
  int wave = blockIdx.x * (blockDim.x >> 6) + (threadIdx.x >> 6);
  int lane = threadIdx.x & 63;
  if (wave >= n) return;
  int beg = row_ptr[wave], end = row_ptr[wave + 1];
  int deg = end - beg;
  int half = lane >> 5;       // which edge of the pair
  int sub = lane & 31;        // float4 slot within the row
  float ax = 0.f, ay = 0.f, az = 0.f, aw = 0.f;
  for (int j0 = 0; j0 < deg; j0 += 64) {
    int li = beg + j0 + lane;
    int idx = csr_src[li < end ? li : (end - 1)];
    float nrm = 0.f;
    if (li < end) nrm = nout ? nout[idx] : 1.f;
    int cnt = deg - j0; if (cnt > 64) cnt = 64;
    int cnt2 = (cnt + 1) >> 1;  // edge pairs this batch
    for (int t0 = 0; t0 < cnt2; t0 += 8) {
      float4 v[8]; float sc[8];
#pragma unroll
      for (int u = 0; u < 8; ++u) {
        int t = t0 + u;
        int e = (t < cnt2) ? (2 * t + half) : 0;   // always 0..63
        int s = __shfl(idx, e, 64);
        float w = __shfl(nrm, e, 64);
        sc[u] = (t < cnt2) ? w : 0.f;
        v[u] = *((const float4*)(x + (size_t)s * DF) + sub);
      }
#pragma unroll
      for (int u = 0; u < 8; ++u) {
        ax += v[u].x * sc[u]; ay += v[u].y * sc[u];
        az += v[u].z * sc[u]; aw += v[u].w * sc[u];
      }
    }
  }
  ax += __shfl_down(ax, 32, 64);
  ay += __shfl_down(ay, 32, 64);
  az += __shfl_down(az, 32, 64);
  aw += __shfl_down(aw, 32, 64);
  if (half == 0) {
    float4 r; r.x = ax; r.y = ay; r.z = az; r.w = aw;
    *((float4*)(agg + (size_t)wave * DF) + sub) = r;
  }
}

// ------ row-wise transform: out[i,:] = (din[i]*(agg[i,:]@W) + b) * sc_out[i] ---
#define TR 32
__device__ __forceinline__ void fma4(float4& acc, float a, const float4& wv) {
  acc.x += a * wv.x; acc.y += a * wv.y; acc.z += a * wv.z; acc.w += a * wv.w;
}
__global__ __launch_bounds__(256) void transform_kernel(
    const float* __restrict__ agg, const float* __restrict__ nin,
    const float* __restrict__ W, const float* __restrict__ bias,
    const float* __restrict__ sc_out, float* __restrict__ out, int n) {
  __shared__ float Ws[DF * DF];   // 64 KiB, natural [k][j]
  __shared__ float As[TR][DF];    // 16 KiB
  for (int i = threadIdx.x; i < DF * DF / 4; i += 256)
    ((float4*)Ws)[i] = ((const float4*)W)[i];
  int c0 = (threadIdx.x & 31) * 4;   // 4 consecutive output cols
  int r0 = (threadIdx.x >> 5) * 4;   // 4 consecutive rows within tile
  float4 b4 = *((const float4*)(bias + c0));
  int ngroups = (n + TR - 1) / TR;
  for (int g = blockIdx.x; g < ngroups; g += gridDim.x) {
    int row0 = g * TR;
    __syncthreads();  // protects As reuse; also covers initial Ws load
    for (int i = threadIdx.x; i < TR * DF / 4; i += 256) {
      int rr = i >> 5;
      int row = row0 + rr;
      float4 v = {0.f, 0.f, 0.f, 0.f};
      if (row < n) v = ((const float4*)(agg + (size_t)row * DF))[i & 31];
      ((float4*)&As[0][0])[i] = v;
    }
    __syncthreads();
    float4 acc0 = {0,0,0,0}, acc1 = {0,0,0,0}, acc2 = {0,0,0,0}, acc3 = {0,0,0,0};
#pragma unroll 4
    for (int k = 0; k < DF; k += 4) {
      float4 a0 = *((const float4*)&As[r0 + 0][k]);
      float4 a1 = *((const float4*)&As[r0 + 1][k]);
      float4 a2 = *((const float4*)&As[r0 + 2][k]);
      float4 a3 = *((const float4*)&As[r0 + 3][k]);
      float4 w0 = *((const float4*)&Ws[(k + 0) * DF + c0]);
      float4 w1 = *((const float4*)&Ws[(k + 1) * DF + c0]);
      float4 w2 = *((const float4*)&Ws[(k + 2) * DF + c0]);
      float4 w3 = *((const float4*)&Ws[(k + 3) * DF + c0]);
      fma4(acc0, a0.x, w0); fma4(acc0, a0.y, w1); fma4(acc0, a0.z, w2); fma4(acc0, a0.w, w3);
      fma4(acc1, a1.x, w0); fma4(acc1, a1.y, w1); fma4(acc1, a1.z, w2); fma4(acc1, a1.w, w3);
      fma4(acc2, a2.x, w0); fma4(acc2, a2.y, w1); fma4(acc2, a2.z, w2); fma4(acc2, a2.w, w3);
      fma4(acc3, a3.x, w0); fma4(acc3, a3.y, w1); fma4(acc3, a3.z, w2); fma4(acc3, a3.w, w3);
    }
    int r = row0 + r0;
#pragma unroll
    for (int q = 0; q < 4; ++q) {
      int rr = r + q;
      if (rr < n) {
        float4 acc = (q == 0) ? acc0 : (q == 1) ? acc1 : (q == 2) ? acc2 : acc3;
        float s = nin[rr];
        float so = sc_out ? sc_out[rr] : 1.f;
        float4 o;
        o.x = (acc.x * s + b4.x) * so;
        o.y = (acc.y * s + b4.y) * so;
        o.z = (acc.z * s + b4.z) * so;
        o.w = (acc.w * s + b4.w) * so;
        *((float4*)(out + (size_t)rr * DF + c0)) = o;
      }
    }
  }
}

extern "C" void kernel_launch(void* const* d_in, const int* in_sizes, int n_in,
                              void* d_out, int out_size, void* d_ws, size_t ws_size,
                              hipStream_t stream) {
  const float* in_feat = (const float*)d_in[0];
  const void*  ei      = d_in[1];
  const float* W1 = (const float*)d_in[2];
  const float* b1 = (const float*)d_in[3];
  const float* W2 = (const float*)d_in[4];
  const float* b2 = (const float*)d_in[5];
  float* out = (float*)d_out;

  const int N = in_sizes[0] / DF;
  const long long E = in_sizes[1] / 2;
  const int nbuck = (N + RNG - 1) >> RSH;          // 391 for N=100K (must be <=512)
  const int M = 2 * nbuck * PB;                    // histogram array length
  const int NB2 = (M + 4095) / 4096;               // scan chunks
  const int chunk = (int)((E + PB - 1) / PB);      // edges per partition block

  size_t off = 0;
  auto take = [&](size_t nb) -> char* {
    char* p = (char*)d_ws + off;
    off += (nb + 255) & ~(size_t)255;
    return p;
  };
  float* agg      = (float*)take((size_t)N * DF * 4);   // 51.2 MB
  int* H          = (int*)take((size_t)M * 4);          // 1.6 MB
  int* Hs         = (int*)take((size_t)(M + 1) * 4);    // 1.6 MB
  int* partials   = (int*)take((size_t)NB2 * 4);
  int* row_ptr    = (int*)take((size_t)(N + 1) * 4);
  float* nout     = (float*)take((size_t)N * 4);
  float* nin      = (float*)take((size_t)N * 4);
  int* flag       = (int*)take(4);
  unsigned* pack_d = (unsigned*)take((size_t)E * 4);    // 6.4 MB
  unsigned char* src_loc = (unsigned char*)take((size_t)E); // 1.6 MB
  int* csr_src    = (int*)take((size_t)E * 4);          // 6.4 MB
  (void)ws_size; (void)n_in; (void)out_size;

  hipMemsetAsync(flag, 0, 4, stream);
  detect_dtype_kernel<<<8, 256, 0, stream>>>((const unsigned*)ei, (long long)in_sizes[1], flag);

  part_count_kernel<<<PB, 256, 0, stream>>>(ei, E, nbuck, chunk, H, flag);
  chunk_sum_kernel<<<NB2, 1024, 0, stream>>>(H, partials, M);
  scan_partials_kernel<<<1, 64, 0, stream>>>(partials, NB2);
  scan_chunk_kernel<<<NB2, 1024, 0, stream>>>(H, partials, Hs, M);
  part_scatter_kernel<<<PB, 256, 0, stream>>>(ei, E, nbuck, chunk, Hs, pack_d, src_loc, flag);
  bucket_build_kernel<<<nbuck, 256, 0, stream>>>(pack_d, Hs, E, N, row_ptr, nin, csr_src);
  src_deg_kernel<<<nbuck, 256, 0, stream>>>(src_loc, Hs, nbuck, E, N, nout);

  int ab = (N + 3) / 4;  // 4 waves (nodes) per 256-thread block
  // conv1: in_feat -> agg -> h1*nout (stored in d_out, pre-scaled for conv2)
  aggregate_kernel<<<ab, 256, 0, stream>>>(in_feat, nout, row_ptr, csr_src, agg, N);
  transform_kernel<<<512, 256, 0, stream>>>(agg, nin, W1, b1, nout, out, N);
  // conv2: h1s (d_out) -> agg -> out (d_out, no scale)
  aggregate_kernel<<<ab, 256, 0, stream>>>(out, nullptr, row_ptr, csr_src, agg, N);
  transform_kernel<<<512, 256, 0, stream>>>(agg, nin, W2, b2, nullptr, out, N);
}

// Round 7
// 342.362 us; speedup vs baseline: 2.4687x; 1.2497x over previous
//
#include <hip/hip_runtime.h>
#include <cstdint>
#include <cstddef>

#define DF 128
#define PB 512        // partition blocks
#define RSH 8         // bucket = node >> RSH
#define RNG 256       // nodes per bucket
#define CAP 6144      // LDS staging capacity (edges) per bucket

// ---------------- bf16 helpers (RNE) ----------------
__device__ __forceinline__ unsigned short f2b(float f) {
  unsigned u = __builtin_bit_cast(unsigned, f);
  u = (u + 0x7FFFu + ((u >> 16) & 1u)) >> 16;
  return (unsigned short)u;
}
__device__ __forceinline__ float b2f(unsigned short h) {
  return __builtin_bit_cast(float, (unsigned)h << 16);
}
__device__ __forceinline__ unsigned pack2(float lo, float hi) {
  return (unsigned)f2b(lo) | ((unsigned)f2b(hi) << 16);
}

// ---------------- edge dtype handling (int32 vs int64 storage) ----------------
__device__ __forceinline__ int edge_at(const void* ei, long long idx, int is32) {
  return is32 ? ((const int*)ei)[idx] : (int)((const long long*)ei)[idx];
}

__global__ void detect_dtype_kernel(const unsigned* __restrict__ ei, long long nelem,
                                    int* __restrict__ flag) {
  long long half = nelem / 2;
  int t = threadIdx.x + blockIdx.x * blockDim.x;
  long long step = (half + 2047) / 2048;
  long long k = (long long)t * step;
  if (k < half && ei[2 * k + 1] != 0) atomicOr(flag, 1);
}

// ---------------- L1: per-block bucket histograms (LDS atomics only) ----------
__global__ __launch_bounds__(256) void part_count_kernel(
    const void* __restrict__ ei, long long E, int nbuck, int chunk,
    int* __restrict__ H, const int* __restrict__ flag) {
  __shared__ int hd[512], hs[512];
  int is32 = *flag;
  int blk = blockIdx.x, t = threadIdx.x;
  for (int i = t; i < 512; i += 256) { hd[i] = 0; hs[i] = 0; }
  __syncthreads();
  long long lo = (long long)blk * chunk;
  long long hi = lo + chunk; if (hi > E) hi = E;
  for (long long e = lo + t; e < hi; e += 256) {
    int s = edge_at(ei, e, is32);
    int d = edge_at(ei, E + e, is32);
    atomicAdd(&hs[s >> RSH], 1);
    atomicAdd(&hd[d >> RSH], 1);
  }
  __syncthreads();
  for (int b = t; b < nbuck; b += 256) {
    H[(size_t)b * PB + blk] = hd[b];
    H[((size_t)nbuck + b) * PB + blk] = hs[b];
  }
}

// ---------------- exclusive scan (3-kernel, shfl-based) ----------------
__device__ __forceinline__ int wave_incl_scan(int v, int lane) {
#pragma unroll
  for (int off = 1; off < 64; off <<= 1) {
    int t = __shfl_up(v, off, 64);
    if (lane >= off) v += t;
  }
  return v;
}

__global__ void chunk_sum_kernel(const int* __restrict__ deg, int* __restrict__ partials, int n) {
  __shared__ int wsum[16];
  int tid = threadIdx.x, lane = tid & 63, wid = tid >> 6;
  int base = blockIdx.x * 4096 + tid * 4;
  int s = 0;
#pragma unroll
  for (int q = 0; q < 4; ++q) { int i = base + q; if (i < n) s += deg[i]; }
#pragma unroll
  for (int off = 32; off; off >>= 1) s += __shfl_down(s, off, 64);
  if (lane == 0) wsum[wid] = s;
  __syncthreads();
  if (tid == 0) {
    int t = 0;
#pragma unroll
    for (int w = 0; w < 16; ++w) t += wsum[w];
    partials[blockIdx.x] = t;
  }
}

__global__ void scan_partials_kernel(int* __restrict__ partials, int nb) {
  int lane = threadIdx.x;
  int carry = 0;
  for (int base = 0; base < nb; base += 64) {
    int i = base + lane;
    int v = (i < nb) ? partials[i] : 0;
    int s = wave_incl_scan(v, lane);
    if (i < nb) partials[i] = s - v + carry;  // exclusive + carry
    carry += __shfl(s, 63, 64);
  }
}

__global__ void scan_chunk_kernel(const int* __restrict__ deg, const int* __restrict__ chunk_off,
                                  int* __restrict__ row_ptr, int n) {
  __shared__ int wsum[16];
  int tid = threadIdx.x, lane = tid & 63, wid = tid >> 6;
  int base = blockIdx.x * 4096 + tid * 4;
  int v0 = (base + 0 < n) ? deg[base + 0] : 0;
  int v1 = (base + 1 < n) ? deg[base + 1] : 0;
  int v2 = (base + 2 < n) ? deg[base + 2] : 0;
  int v3 = (base + 3 < n) ? deg[base + 3] : 0;
  int p0 = v0, p1 = p0 + v1, p2 = p1 + v2, p3 = p2 + v3;
  int ws = wave_incl_scan(p3, lane);
  if (lane == 63) wsum[wid] = ws;
  __syncthreads();
  if (wid == 0) {
    int x = (lane < 16) ? wsum[lane] : 0;
    x = wave_incl_scan(x, lane);
    if (lane < 16) wsum[lane] = x;
  }
  __syncthreads();
  int off = (wid > 0 ? wsum[wid - 1] : 0) + (ws - p3) + chunk_off[blockIdx.x];
  if (base + 0 < n) row_ptr[base + 1] = off + p0;
  if (base + 1 < n) row_ptr[base + 2] = off + p1;
  if (base + 2 < n) row_ptr[base + 3] = off + p2;
  if (base + 3 < n) row_ptr[base + 4] = off + p3;
  if (blockIdx.x == 0 && tid == 0) row_ptr[0] = 0;
}

// ---------------- L1b: scatter into bucket segments (LDS ranks, plain stores) --
__global__ __launch_bounds__(256) void part_scatter_kernel(
    const void* __restrict__ ei, long long E, int nbuck, int chunk,
    const int* __restrict__ Hs, unsigned* __restrict__ pack_d,
    unsigned char* __restrict__ src_loc, const int* __restrict__ flag) {
  __shared__ int hd[512], hs[512], bd[512], bs[512];
  int is32 = *flag;
  int blk = blockIdx.x, t = threadIdx.x;
  for (int i = t; i < 512; i += 256) { hd[i] = 0; hs[i] = 0; }
  __syncthreads();
  for (int b = t; b < nbuck; b += 256) {
    bd[b] = Hs[(size_t)b * PB + blk];
    bs[b] = Hs[((size_t)nbuck + b) * PB + blk] - (int)E;
  }
  __syncthreads();
  long long lo = (long long)blk * chunk;
  long long hi = lo + chunk; if (hi > E) hi = E;
  for (long long e = lo + t; e < hi; e += 256) {
    int s = edge_at(ei, e, is32);
    int d = edge_at(ei, E + e, is32);
    int kb = d >> RSH;
    int rd = atomicAdd(&hd[kb], 1);
    pack_d[bd[kb] + rd] = ((unsigned)(d & (RNG - 1)) << 24) | (unsigned)s;
    int ks = s >> RSH;
    int rs = atomicAdd(&hs[ks], 1);
    src_loc[bs[ks] + rs] = (unsigned char)(s & (RNG - 1));
  }
}

// ---------------- L2: per-bucket CSR build (row_ptr, nin, csr_src) -------------
__global__ __launch_bounds__(256) void bucket_build_kernel(
    const unsigned* __restrict__ pack_d, const int* __restrict__ Hs,
    long long E, int n, int* __restrict__ row_ptr, float* __restrict__ nin,
    int* __restrict__ csr_src) {
  __shared__ unsigned stage[CAP];
  __shared__ int cnt[RNG], cur[RNG], woff[4];
  int b = blockIdx.x, t = threadIdx.x;
  int lane = t & 63, wv = t >> 6;
  int start = Hs[(size_t)b * PB];
  int end = Hs[(size_t)(b + 1) * PB];
  int len = end - start;
  cnt[t] = 0;
  __syncthreads();
  bool fits = (len <= CAP);
  for (int i = t; i < len; i += 256) {
    unsigned p = pack_d[start + i];
    if (fits) stage[i] = p;
    atomicAdd(&cnt[p >> 24], 1);
  }
  __syncthreads();
  int dreg = cnt[t];
  int isc = wave_incl_scan(dreg, lane);
  if (lane == 63) woff[wv] = isc;
  __syncthreads();
  int add = 0;
#pragma unroll
  for (int w = 0; w < 4; ++w) if (w < wv) add += woff[w];
  int excl = isc - dreg + add;
  int nd = b * RNG + t;
  if (nd < n) {
    row_ptr[nd] = start + excl;
    nin[nd] = rsqrtf((float)(dreg > 1 ? dreg : 1));
  }
  if (b == (int)gridDim.x - 1 && t == 0) row_ptr[n] = (int)E;
  cur[t] = excl;
  __syncthreads();
  for (int i = t; i < len; i += 256) {
    unsigned p = fits ? stage[i] : pack_d[start + i];
    int dl = (int)(p >> 24);
    int r = atomicAdd(&cur[dl], 1);
    csr_src[start + r] = (int)(p & 0xFFFFFFu);
  }
}

// ---------------- L2s: per-bucket src-degree count -> nout ---------------------
__global__ __launch_bounds__(256) void src_deg_kernel(
    const unsigned char* __restrict__ src_loc, const int* __restrict__ Hs,
    int nbuck, long long E, int n, float* __restrict__ nout) {
  __shared__ int cnt[RNG];
  int b = blockIdx.x, t = threadIdx.x;
  int start = Hs[(size_t)(nbuck + b) * PB] - (int)E;
  int end = Hs[(size_t)(nbuck + b + 1) * PB] - (int)E;
  cnt[t] = 0;
  __syncthreads();
  for (int i = start + t; i < end; i += 256) atomicAdd(&cnt[src_loc[i]], 1);
  __syncthreads();
  int nd = b * RNG + t;
  if (nd < n) nout[nd] = rsqrtf((float)(cnt[t] > 1 ? cnt[t] : 1));
}

// ---------------- prescale: xh[i,:] = bf16(x[i,:] * nout[i]) -------------------
__global__ __launch_bounds__(256) void prescale_kernel(
    const float* __restrict__ x, const float* __restrict__ nout,
    unsigned short* __restrict__ xh, int n) {
  long long base = ((long long)blockIdx.x * 256 + threadIdx.x) * 8;
  if (base >= (long long)n * DF) return;
  float s = nout[(int)(base >> 7)];
  float4 a = *((const float4*)(x + base));
  float4 b = *((const float4*)(x + base + 4));
  uint4 o;
  o.x = pack2(a.x * s, a.y * s);
  o.y = pack2(a.z * s, a.w * s);
  o.z = pack2(b.x * s, b.y * s);
  o.w = pack2(b.z * s, b.w * s);
  *((uint4*)(xh + base)) = o;
}

// ---------------- aggregation: one wave per dst node, bf16 256B rows -----------
// Input rows are pre-scaled by dout, so no per-edge norm lookup. Lanes 0-31
// handle even edges, 32-63 odd edges; 32 lanes x ushort4 (8B) = one 256B row.
__global__ __launch_bounds__(256) void aggregate_bf16_kernel(
    const unsigned short* __restrict__ xh, const int* __restrict__ row_ptr,
    const int* __restrict__ csr_src, float* __restrict__ agg, int n) {
  int wave = blockIdx.x * (blockDim.x >> 6) + (threadIdx.x >> 6);
  int lane = threadIdx.x & 63;
  if (wave >= n) return;
  int beg = row_ptr[wave], end = row_ptr[wave + 1];
  int deg = end - beg;
  int half = lane >> 5;       // which edge of the pair
  int sub = lane & 31;        // ushort4 slot within the 256B row
  float ax = 0.f, ay = 0.f, az = 0.f, aw = 0.f;
  for (int j0 = 0; j0 < deg; j0 += 64) {
    int li = beg + j0 + lane;
    int idx = csr_src[li < end ? li : (end - 1)];
    int cnt = deg - j0; if (cnt > 64) cnt = 64;
    int tfull = (cnt >> 4) << 3;   // pairs fully valid, in groups of 8
    for (int t0 = 0; t0 < tfull; t0 += 8) {
      ushort4 v[8];
#pragma unroll
      for (int u = 0; u < 8; ++u) {
        int s = __shfl(idx, 2 * (t0 + u) + half, 64);
        v[u] = *((const ushort4*)(xh + (size_t)s * DF) + sub);
      }
#pragma unroll
      for (int u = 0; u < 8; ++u) {
        ax += b2f(v[u].x); ay += b2f(v[u].y);
        az += b2f(v[u].z); aw += b2f(v[u].w);
      }
    }
    int cnt2 = (cnt + 1) >> 1;
    for (int t = tfull; t < cnt2; ++t) {
      int p = 2 * t + half;
      int s = __shfl(idx, p, 64);
      float m = (p < cnt) ? 1.f : 0.f;
      ushort4 v = *((const ushort4*)(xh + (size_t)s * DF) + sub);
      ax += b2f(v.x) * m; ay += b2f(v.y) * m;
      az += b2f(v.z) * m; aw += b2f(v.w) * m;
    }
  }
  ax += __shfl_down(ax, 32, 64);
  ay += __shfl_down(ay, 32, 64);
  az += __shfl_down(az, 32, 64);
  aw += __shfl_down(aw, 32, 64);
  if (half == 0) {
    float4 r; r.x = ax; r.y = ay; r.z = az; r.w = aw;
    *((float4*)(agg + (size_t)wave * DF) + sub) = r;
  }
}

// ------ row-wise transform: out[i,:] = (din[i]*(agg[i,:]@W) + b) * sc_out[i] ---
// BF16OUT=1 -> packed bf16 output (for the next gather); else f32. In-place
// f32 output (out==agg) is safe: each tile is staged to LDS before writes.
#define TR 32
__device__ __forceinline__ void fma4(float4& acc, float a, const float4& wv) {
  acc.x += a * wv.x; acc.y += a * wv.y; acc.z += a * wv.z; acc.w += a * wv.w;
}
template <int BF16OUT>
__global__ __launch_bounds__(256) void transform_kernel(
    const float* __restrict__ agg, const float* __restrict__ nin,
    const float* __restrict__ W, const float* __restrict__ bias,
    const float* __restrict__ sc_out, void* __restrict__ outp, int n) {
  __shared__ float Ws[DF * DF];   // 64 KiB, natural [k][j]
  __shared__ float As[TR][DF];    // 16 KiB
  for (int i = threadIdx.x; i < DF * DF / 4; i += 256)
    ((float4*)Ws)[i] = ((const float4*)W)[i];
  int c0 = (threadIdx.x & 31) * 4;   // 4 consecutive output cols
  int r0 = (threadIdx.x >> 5) * 4;   // 4 consecutive rows within tile
  float4 b4 = *((const float4*)(bias + c0));
  int ngroups = (n + TR - 1) / TR;
  for (int g = blockIdx.x; g < ngroups; g += gridDim.x) {
    int row0 = g * TR;
    __syncthreads();  // protects As reuse; also covers initial Ws load
    for (int i = threadIdx.x; i < TR * DF / 4; i += 256) {
      int rr = i >> 5;
      int row = row0 + rr;
      float4 v = {0.f, 0.f, 0.f, 0.f};
      if (row < n) v = ((const float4*)(agg + (size_t)row * DF))[i & 31];
      ((float4*)&As[0][0])[i] = v;
    }
    __syncthreads();
    float4 acc0 = {0,0,0,0}, acc1 = {0,0,0,0}, acc2 = {0,0,0,0}, acc3 = {0,0,0,0};
#pragma unroll 4
    for (int k = 0; k < DF; k += 4) {
      float4 a0 = *((const float4*)&As[r0 + 0][k]);
      float4 a1 = *((const float4*)&As[r0 + 1][k]);
      float4 a2 = *((const float4*)&As[r0 + 2][k]);
      float4 a3 = *((const float4*)&As[r0 + 3][k]);
      float4 w0 = *((const float4*)&Ws[(k + 0) * DF + c0]);
      float4 w1 = *((const float4*)&Ws[(k + 1) * DF + c0]);
      float4 w2 = *((const float4*)&Ws[(k + 2) * DF + c0]);
      float4 w3 = *((const float4*)&Ws[(k + 3) * DF + c0]);
      fma4(acc0, a0.x, w0); fma4(acc0, a0.y, w1); fma4(acc0, a0.z, w2); fma4(acc0, a0.w, w3);
      fma4(acc1, a1.x, w0); fma4(acc1, a1.y, w1); fma4(acc1, a1.z, w2); fma4(acc1, a1.w, w3);
      fma4(acc2, a2.x, w0); fma4(acc2, a2.y, w1); fma4(acc2, a2.z, w2); fma4(acc2, a2.w, w3);
      fma4(acc3, a3.x, w0); fma4(acc3, a3.y, w1); fma4(acc3, a3.z, w2); fma4(acc3, a3.w, w3);
    }
    int r = row0 + r0;
#pragma unroll
    for (int q = 0; q < 4; ++q) {
      int rr = r + q;
      if (rr < n) {
        float4 acc = (q == 0) ? acc0 : (q == 1) ? acc1 : (q == 2) ? acc2 : acc3;
        float s = nin[rr];
        float so = sc_out ? sc_out[rr] : 1.f;
        float4 o;
        o.x = (acc.x * s + b4.x) * so;
        o.y = (acc.y * s + b4.y) * so;
        o.z = (acc.z * s + b4.z) * so;
        o.w = (acc.w * s + b4.w) * so;
        if (BF16OUT) {
          uint2 pk; pk.x = pack2(o.x, o.y); pk.y = pack2(o.z, o.w);
          *((uint2*)((unsigned short*)outp + (size_t)rr * DF + c0)) = pk;
        } else {
          *((float4*)((float*)outp + (size_t)rr * DF + c0)) = o;
        }
      }
    }
  }
}

extern "C" void kernel_launch(void* const* d_in, const int* in_sizes, int n_in,
                              void* d_out, int out_size, void* d_ws, size_t ws_size,
                              hipStream_t stream) {
  const float* in_feat = (const float*)d_in[0];
  const void*  ei      = d_in[1];
  const float* W1 = (const float*)d_in[2];
  const float* b1 = (const float*)d_in[3];
  const float* W2 = (const float*)d_in[4];
  const float* b2 = (const float*)d_in[5];
  float* out = (float*)d_out;

  const int N = in_sizes[0] / DF;
  const long long E = in_sizes[1] / 2;
  const int nbuck = (N + RNG - 1) >> RSH;          // 391 for N=100K (must be <=512)
  const int M = 2 * nbuck * PB;                    // histogram array length
  const int NB2 = (M + 4095) / 4096;               // scan chunks
  const int chunk = (int)((E + PB - 1) / PB);      // edges per partition block

  size_t off = 0;
  auto take = [&](size_t nb) -> char* {
    char* p = (char*)d_ws + off;
    off += (nb + 255) & ~(size_t)255;
    return p;
  };
  int* H          = (int*)take((size_t)M * 4);          // 1.6 MB
  int* Hs         = (int*)take((size_t)(M + 1) * 4);    // 1.6 MB
  int* partials   = (int*)take((size_t)NB2 * 4);
  int* row_ptr    = (int*)take((size_t)(N + 1) * 4);
  float* nout     = (float*)take((size_t)N * 4);
  float* nin      = (float*)take((size_t)N * 4);
  int* flag       = (int*)take(4);
  unsigned* pack_d = (unsigned*)take((size_t)E * 4);    // 6.4 MB
  unsigned char* src_loc = (unsigned char*)take((size_t)E); // 1.6 MB
  int* csr_src    = (int*)take((size_t)E * 4);          // 6.4 MB
  unsigned short* x1h = (unsigned short*)take((size_t)N * DF * 2); // 25.6 MB
  unsigned short* h1h = (unsigned short*)take((size_t)N * DF * 2); // 25.6 MB
  float* agg = out;  // d_out doubles as the f32 aggregation scratch
  (void)ws_size; (void)n_in; (void)out_size;

  hipMemsetAsync(flag, 0, 4, stream);
  detect_dtype_kernel<<<8, 256, 0, stream>>>((const unsigned*)ei, (long long)in_sizes[1], flag);

  part_count_kernel<<<PB, 256, 0, stream>>>(ei, E, nbuck, chunk, H, flag);
  chunk_sum_kernel<<<NB2, 1024, 0, stream>>>(H, partials, M);
  scan_partials_kernel<<<1, 64, 0, stream>>>(partials, NB2);
  scan_chunk_kernel<<<NB2, 1024, 0, stream>>>(H, partials, Hs, M);
  part_scatter_kernel<<<PB, 256, 0, stream>>>(ei, E, nbuck, chunk, Hs, pack_d, src_loc, flag);
  bucket_build_kernel<<<nbuck, 256, 0, stream>>>(pack_d, Hs, E, N, row_ptr, nin, csr_src);
  src_deg_kernel<<<nbuck, 256, 0, stream>>>(src_loc, Hs, nbuck, E, N, nout);

  // conv1 operand: x1h = bf16(in_feat * dout)
  int pb = (int)(((long long)N * DF / 8 + 255) / 256);
  prescale_kernel<<<pb, 256, 0, stream>>>(in_feat, nout, x1h, N);

  int ab = (N + 3) / 4;  // 4 waves (nodes) per 256-thread block
  // conv1: x1h -> agg(d_out) -> h1h = bf16((agg*nin)@W1+b1)*dout
  aggregate_bf16_kernel<<<ab, 256, 0, stream>>>(x1h, row_ptr, csr_src, agg, N);
  transform_kernel<1><<<512, 256, 0, stream>>>(agg, nin, W1, b1, nout, h1h, N);
  // conv2: h1h -> agg(d_out) -> out (in-place f32)
  aggregate_bf16_kernel<<<ab, 256, 0, stream>>>(h1h, row_ptr, csr_src, agg, N);
  transform_kernel<0><<<512, 256, 0, stream>>>(agg, nin, W2, b2, nullptr, out, N);
}

// Round 8
// 313.141 us; speedup vs baseline: 2.6991x; 1.0933x over previous
//
#include <hip/hip_runtime.h>
#include <cstdint>
#include <cstddef>

#define DF 128
#define PB 512        // partition blocks
#define RSH 8         // bucket = node >> RSH
#define RNG 256       // nodes per bucket
#define CAP 6144      // LDS staging capacity (edges) per bucket

typedef short bf16x8 __attribute__((ext_vector_type(8)));
typedef float f32x4 __attribute__((ext_vector_type(4)));

// ---------------- bf16 helpers (RNE) ----------------
__device__ __forceinline__ unsigned short f2b(float f) {
  unsigned u = __builtin_bit_cast(unsigned, f);
  u = (u + 0x7FFFu + ((u >> 16) & 1u)) >> 16;
  return (unsigned short)u;
}
__device__ __forceinline__ float b2f(unsigned short h) {
  return __builtin_bit_cast(float, (unsigned)h << 16);
}
__device__ __forceinline__ unsigned pack2(float lo, float hi) {
  return (unsigned)f2b(lo) | ((unsigned)f2b(hi) << 16);
}

// ---------------- edge dtype handling (int32 vs int64 storage) ----------------
__device__ __forceinline__ int edge_at(const void* ei, long long idx, int is32) {
  return is32 ? ((const int*)ei)[idx] : (int)((const long long*)ei)[idx];
}

__global__ void detect_dtype_kernel(const unsigned* __restrict__ ei, long long nelem,
                                    int* __restrict__ flag) {
  long long half = nelem / 2;
  int t = threadIdx.x + blockIdx.x * blockDim.x;
  long long step = (half + 2047) / 2048;
  long long k = (long long)t * step;
  if (k < half && ei[2 * k + 1] != 0) atomicOr(flag, 1);
}

// ---------------- L1: per-block bucket histograms (LDS atomics only) ----------
__global__ __launch_bounds__(256) void part_count_kernel(
    const void* __restrict__ ei, long long E, int nbuck, int chunk,
    int* __restrict__ H, const int* __restrict__ flag) {
  __shared__ int hd[512], hs[512];
  int is32 = *flag;
  int blk = blockIdx.x, t = threadIdx.x;
  for (int i = t; i < 512; i += 256) { hd[i] = 0; hs[i] = 0; }
  __syncthreads();
  long long lo = (long long)blk * chunk;
  long long hi = lo + chunk; if (hi > E) hi = E;
  for (long long e = lo + t; e < hi; e += 256) {
    int s = edge_at(ei, e, is32);
    int d = edge_at(ei, E + e, is32);
    atomicAdd(&hs[s >> RSH], 1);
    atomicAdd(&hd[d >> RSH], 1);
  }
  __syncthreads();
  for (int b = t; b < nbuck; b += 256) {
    H[(size_t)b * PB + blk] = hd[b];
    H[((size_t)nbuck + b) * PB + blk] = hs[b];
  }
}

// ---------------- exclusive scan (3-kernel, shfl-based) ----------------
__device__ __forceinline__ int wave_incl_scan(int v, int lane) {
#pragma unroll
  for (int off = 1; off < 64; off <<= 1) {
    int t = __shfl_up(v, off, 64);
    if (lane >= off) v += t;
  }
  return v;
}

__global__ void chunk_sum_kernel(const int* __restrict__ deg, int* __restrict__ partials, int n) {
  __shared__ int wsum[16];
  int tid = threadIdx.x, lane = tid & 63, wid = tid >> 6;
  int base = blockIdx.x * 4096 + tid * 4;
  int s = 0;
#pragma unroll
  for (int q = 0; q < 4; ++q) { int i = base + q; if (i < n) s += deg[i]; }
#pragma unroll
  for (int off = 32; off; off >>= 1) s += __shfl_down(s, off, 64);
  if (lane == 0) wsum[wid] = s;
  __syncthreads();
  if (tid == 0) {
    int t = 0;
#pragma unroll
    for (int w = 0; w < 16; ++w) t += wsum[w];
    partials[blockIdx.x] = t;
  }
}

__global__ void scan_partials_kernel(int* __restrict__ partials, int nb) {
  int lane = threadIdx.x;
  int carry = 0;
  for (int base = 0; base < nb; base += 64) {
    int i = base + lane;
    int v = (i < nb) ? partials[i] : 0;
    int s = wave_incl_scan(v, lane);
    if (i < nb) partials[i] = s - v + carry;  // exclusive + carry
    carry += __shfl(s, 63, 64);
  }
}

__global__ void scan_chunk_kernel(const int* __restrict__ deg, const int* __restrict__ chunk_off,
                                  int* __restrict__ row_ptr, int n) {
  __shared__ int wsum[16];
  int tid = threadIdx.x, lane = tid & 63, wid = tid >> 6;
  int base = blockIdx.x * 4096 + tid * 4;
  int v0 = (base + 0 < n) ? deg[base + 0] : 0;
  int v1 = (base + 1 < n) ? deg[base + 1] : 0;
  int v2 = (base + 2 < n) ? deg[base + 2] : 0;
  int v3 = (base + 3 < n) ? deg[base + 3] : 0;
  int p0 = v0, p1 = p0 + v1, p2 = p1 + v2, p3 = p2 + v3;
  int ws = wave_incl_scan(p3, lane);
  if (lane == 63) wsum[wid] = ws;
  __syncthreads();
  if (wid == 0) {
    int x = (lane < 16) ? wsum[lane] : 0;
    x = wave_incl_scan(x, lane);
    if (lane < 16) wsum[lane] = x;
  }
  __syncthreads();
  int off = (wid > 0 ? wsum[wid - 1] : 0) + (ws - p3) + chunk_off[blockIdx.x];
  if (base + 0 < n) row_ptr[base + 1] = off + p0;
  if (base + 1 < n) row_ptr[base + 2] = off + p1;
  if (base + 2 < n) row_ptr[base + 3] = off + p2;
  if (base + 3 < n) row_ptr[base + 4] = off + p3;
  if (blockIdx.x == 0 && tid == 0) row_ptr[0] = 0;
}

// ---------------- L1b: scatter into bucket segments (LDS ranks, plain stores) --
__global__ __launch_bounds__(256) void part_scatter_kernel(
    const void* __restrict__ ei, long long E, int nbuck, int chunk,
    const int* __restrict__ Hs, unsigned* __restrict__ pack_d,
    unsigned char* __restrict__ src_loc, const int* __restrict__ flag) {
  __shared__ int hd[512], hs[512], bd[512], bs[512];
  int is32 = *flag;
  int blk = blockIdx.x, t = threadIdx.x;
  for (int i = t; i < 512; i += 256) { hd[i] = 0; hs[i] = 0; }
  __syncthreads();
  for (int b = t; b < nbuck; b += 256) {
    bd[b] = Hs[(size_t)b * PB + blk];
    bs[b] = Hs[((size_t)nbuck + b) * PB + blk] - (int)E;
  }
  __syncthreads();
  long long lo = (long long)blk * chunk;
  long long hi = lo + chunk; if (hi > E) hi = E;
  for (long long e = lo + t; e < hi; e += 256) {
    int s = edge_at(ei, e, is32);
    int d = edge_at(ei, E + e, is32);
    int kb = d >> RSH;
    int rd = atomicAdd(&hd[kb], 1);
    pack_d[bd[kb] + rd] = ((unsigned)(d & (RNG - 1)) << 24) | (unsigned)s;
    int ks = s >> RSH;
    int rs = atomicAdd(&hs[ks], 1);
    src_loc[bs[ks] + rs] = (unsigned char)(s & (RNG - 1));
  }
}

// ---------------- L2: per-bucket CSR build (row_ptr, nin, csr_src) -------------
__global__ __launch_bounds__(256) void bucket_build_kernel(
    const unsigned* __restrict__ pack_d, const int* __restrict__ Hs,
    long long E, int n, int* __restrict__ row_ptr, float* __restrict__ nin,
    int* __restrict__ csr_src) {
  __shared__ unsigned stage[CAP];
  __shared__ int cnt[RNG], cur[RNG], woff[4];
  int b = blockIdx.x, t = threadIdx.x;
  int lane = t & 63, wv = t >> 6;
  int start = Hs[(size_t)b * PB];
  int end = Hs[(size_t)(b + 1) * PB];
  int len = end - start;
  cnt[t] = 0;
  __syncthreads();
  bool fits = (len <= CAP);
  for (int i = t; i < len; i += 256) {
    unsigned p = pack_d[start + i];
    if (fits) stage[i] = p;
    atomicAdd(&cnt[p >> 24], 1);
  }
  __syncthreads();
  int dreg = cnt[t];
  int isc = wave_incl_scan(dreg, lane);
  if (lane == 63) woff[wv] = isc;
  __syncthreads();
  int add = 0;
#pragma unroll
  for (int w = 0; w < 4; ++w) if (w < wv) add += woff[w];
  int excl = isc - dreg + add;
  int nd = b * RNG + t;
  if (nd < n) {
    row_ptr[nd] = start + excl;
    nin[nd] = rsqrtf((float)(dreg > 1 ? dreg : 1));
  }
  if (b == (int)gridDim.x - 1 && t == 0) row_ptr[n] = (int)E;
  cur[t] = excl;
  __syncthreads();
  for (int i = t; i < len; i += 256) {
    unsigned p = fits ? stage[i] : pack_d[start + i];
    int dl = (int)(p >> 24);
    int r = atomicAdd(&cur[dl], 1);
    csr_src[start + r] = (int)(p & 0xFFFFFFu);
  }
}

// ---------------- L2s: per-bucket src-degree count -> nout ---------------------
__global__ __launch_bounds__(256) void src_deg_kernel(
    const unsigned char* __restrict__ src_loc, const int* __restrict__ Hs,
    int nbuck, long long E, int n, float* __restrict__ nout) {
  __shared__ int cnt[RNG];
  int b = blockIdx.x, t = threadIdx.x;
  int start = Hs[(size_t)(nbuck + b) * PB] - (int)E;
  int end = Hs[(size_t)(nbuck + b + 1) * PB] - (int)E;
  cnt[t] = 0;
  __syncthreads();
  for (int i = start + t; i < end; i += 256) atomicAdd(&cnt[src_loc[i]], 1);
  __syncthreads();
  int nd = b * RNG + t;
  if (nd < n) nout[nd] = rsqrtf((float)(cnt[t] > 1 ? cnt[t] : 1));
}

// ---------------- prescale: xh[i,:] = bf16(x[i,:] * nout[i]) -------------------
__global__ __launch_bounds__(256) void prescale_kernel(
    const float* __restrict__ x, const float* __restrict__ nout,
    unsigned short* __restrict__ xh, int n) {
  long long base = ((long long)blockIdx.x * 256 + threadIdx.x) * 8;
  if (base >= (long long)n * DF) return;
  float s = nout[(int)(base >> 7)];
  float4 a = *((const float4*)(x + base));
  float4 b = *((const float4*)(x + base + 4));
  uint4 o;
  o.x = pack2(a.x * s, a.y * s);
  o.y = pack2(a.z * s, a.w * s);
  o.z = pack2(b.x * s, b.y * s);
  o.w = pack2(b.z * s, b.w * s);
  *((uint4*)(xh + base)) = o;
}

// ------ W prep: swizzle W1,W2 into MFMA B-fragment order, hi/lo bf16 split -----
// Layout: [w(2)][part(2)][tile(32)=jb*4+ks][lane(64)] x 16B (8 bf16, contiguous k)
// Fragment: lane l of tile (jb,ks) holds W[k][c], c=jb*16+(l&15),
//           k=ks*32+(l>>4)*8+e, e=0..7.
__global__ void w_prep_kernel(const float* __restrict__ W1, const float* __restrict__ W2,
                              unsigned short* __restrict__ Wswz) {
  int chunk = blockIdx.x * 256 + threadIdx.x;   // 0..8191
  if (chunk >= 8192) return;
  int w = chunk >> 12;
  int rem = chunk & 4095;
  int part = rem >> 11;
  int t = (rem >> 6) & 31;
  int l = rem & 63;
  int jb = t >> 2, ks = t & 3;
  const float* W = w ? W2 : W1;
  int c = jb * 16 + (l & 15);
  int k0 = ks * 32 + ((l >> 4) << 3);
  unsigned v[4];
#pragma unroll
  for (int p = 0; p < 4; ++p) {
    float f0 = W[(size_t)(k0 + 2 * p) * DF + c];
    float f1 = W[(size_t)(k0 + 2 * p + 1) * DF + c];
    unsigned short h0 = f2b(f0), h1 = f2b(f1);
    unsigned short o0 = part ? f2b(f0 - b2f(h0)) : h0;
    unsigned short o1 = part ? f2b(f1 - b2f(h1)) : h1;
    v[p] = (unsigned)o0 | ((unsigned)o1 << 16);
  }
  uint4 o; o.x = v[0]; o.y = v[1]; o.z = v[2]; o.w = v[3];
  ((uint4*)Wswz)[chunk] = o;
}

// ---------------- aggregation: one wave per dst node, bf16 256B rows -----------
// Input rows pre-scaled by dout. Output bf16 (feeds MFMA transform directly).
__global__ __launch_bounds__(256) void aggregate_bf16_kernel(
    const unsigned short* __restrict__ xh, const int* __restrict__ row_ptr,
    const int* __restrict__ csr_src, unsigned short* __restrict__ aggh, int n) {
  int wave = blockIdx.x * (blockDim.x >> 6) + (threadIdx.x >> 6);
  int lane = threadIdx.x & 63;
  if (wave >= n) return;
  int beg = row_ptr[wave], end = row_ptr[wave + 1];
  int deg = end - beg;
  int half = lane >> 5;       // which edge of the pair
  int sub = lane & 31;        // ushort4 slot within the 256B row
  float ax = 0.f, ay = 0.f, az = 0.f, aw = 0.f;
  for (int j0 = 0; j0 < deg; j0 += 64) {
    int li = beg + j0 + lane;
    int idx = csr_src[li < end ? li : (end - 1)];
    int cnt = deg - j0; if (cnt > 64) cnt = 64;
    int tfull = (cnt >> 4) << 3;   // pairs fully valid, in groups of 8
    for (int t0 = 0; t0 < tfull; t0 += 8) {
      ushort4 v[8];
#pragma unroll
      for (int u = 0; u < 8; ++u) {
        int s = __shfl(idx, 2 * (t0 + u) + half, 64);
        v[u] = *((const ushort4*)(xh + (size_t)s * DF) + sub);
      }
#pragma unroll
      for (int u = 0; u < 8; ++u) {
        ax += b2f(v[u].x); ay += b2f(v[u].y);
        az += b2f(v[u].z); aw += b2f(v[u].w);
      }
    }
    int cnt2 = (cnt + 1) >> 1;
    for (int t = tfull; t < cnt2; ++t) {
      int p = 2 * t + half;
      int s = __shfl(idx, p, 64);
      float m = (p < cnt) ? 1.f : 0.f;
      ushort4 v = *((const ushort4*)(xh + (size_t)s * DF) + sub);
      ax += b2f(v.x) * m; ay += b2f(v.y) * m;
      az += b2f(v.z) * m; aw += b2f(v.w) * m;
    }
  }
  ax += __shfl_down(ax, 32, 64);
  ay += __shfl_down(ay, 32, 64);
  az += __shfl_down(az, 32, 64);
  aw += __shfl_down(aw, 32, 64);
  if (half == 0) {
    uint2 pk; pk.x = pack2(ax, ay); pk.y = pack2(az, aw);
    *((uint2*)(aggh + (size_t)wave * DF + sub * 4)) = pk;
  }
}

// ------ MFMA transform: out[r,:] = (nin[r]*(aggh[r,:]@W) + b) * sc_out[r] ------
// One wave per 16-row stripe; W (hi+lo bf16) resident in 64KiB LDS; single
// barrier after staging, none in the tile loop.
template <int BF16OUT>
__global__ __launch_bounds__(256) void transform_mfma_kernel(
    const unsigned short* __restrict__ aggh, const unsigned short* __restrict__ Wswz,
    const float* __restrict__ nin, const float* __restrict__ bias,
    const float* __restrict__ sc_out, void* __restrict__ outp, int n, int ntiles) {
  __shared__ uint4 Wl[4096];   // 64 KiB: [part(2)][tile(32)][lane(64)]
  int tid = threadIdx.x;
  for (int i = tid; i < 4096; i += 256) Wl[i] = ((const uint4*)Wswz)[i];
  __syncthreads();
  int l = tid & 63, wv = tid >> 6;
  int lr = l & 15, lg = l >> 4;
  for (int tile = blockIdx.x; tile < ntiles; tile += gridDim.x) {
    int rowbase = tile * 64 + wv * 16;
    int r_eff = rowbase + lr; if (r_eff > n - 1) r_eff = n - 1;
    const unsigned short* arow = aggh + (size_t)r_eff * DF + (lg << 3);
    bf16x8 a0 = *(const bf16x8*)(arow);
    bf16x8 a1 = *(const bf16x8*)(arow + 32);
    bf16x8 a2 = *(const bf16x8*)(arow + 64);
    bf16x8 a3 = *(const bf16x8*)(arow + 96);
    f32x4 acc[8];
#pragma unroll
    for (int jb = 0; jb < 8; ++jb) acc[jb] = (f32x4){0.f, 0.f, 0.f, 0.f};
#pragma unroll
    for (int ks = 0; ks < 4; ++ks) {
      bf16x8 a = (ks == 0) ? a0 : (ks == 1) ? a1 : (ks == 2) ? a2 : a3;
#pragma unroll
      for (int jb = 0; jb < 8; ++jb) {
        bf16x8 bh = *(const bf16x8*)&Wl[(jb * 4 + ks) * 64 + l];
        acc[jb] = __builtin_amdgcn_mfma_f32_16x16x32_bf16(a, bh, acc[jb], 0, 0, 0);
        bf16x8 bl = *(const bf16x8*)&Wl[2048 + (jb * 4 + ks) * 64 + l];
        acc[jb] = __builtin_amdgcn_mfma_f32_16x16x32_bf16(a, bl, acc[jb], 0, 0, 0);
      }
    }
    float ninq[4], soq[4];
#pragma unroll
    for (int q = 0; q < 4; ++q) {
      int r = rowbase + lg * 4 + q;
      ninq[q] = (r < n) ? nin[r] : 0.f;
      soq[q] = (r < n) ? (sc_out ? sc_out[r] : 1.f) : 0.f;
    }
#pragma unroll
    for (int jb = 0; jb < 8; ++jb) {
      int c = jb * 16 + lr;
      float bj = bias[c];
#pragma unroll
      for (int q = 0; q < 4; ++q) {
        int r = rowbase + lg * 4 + q;
        if (r < n) {
          float val = (acc[jb][q] * ninq[q] + bj) * soq[q];
          if (BF16OUT) {
            ((unsigned short*)outp)[(size_t)r * DF + c] = f2b(val);
          } else {
            ((float*)outp)[(size_t)r * DF + c] = val;
          }
        }
      }
    }
  }
}

extern "C" void kernel_launch(void* const* d_in, const int* in_sizes, int n_in,
                              void* d_out, int out_size, void* d_ws, size_t ws_size,
                              hipStream_t stream) {
  const float* in_feat = (const float*)d_in[0];
  const void*  ei      = d_in[1];
  const float* W1 = (const float*)d_in[2];
  const float* b1 = (const float*)d_in[3];
  const float* W2 = (const float*)d_in[4];
  const float* b2 = (const float*)d_in[5];
  float* out = (float*)d_out;

  const int N = in_sizes[0] / DF;
  const long long E = in_sizes[1] / 2;
  const int nbuck = (N + RNG - 1) >> RSH;          // 391 for N=100K (must be <=512)
  const int M = 2 * nbuck * PB;                    // histogram array length
  const int NB2 = (M + 4095) / 4096;               // scan chunks
  const int chunk = (int)((E + PB - 1) / PB);      // edges per partition block
  const int ntiles = (N + 63) / 64;

  size_t off = 0;
  auto take = [&](size_t nb) -> char* {
    char* p = (char*)d_ws + off;
    off += (nb + 255) & ~(size_t)255;
    return p;
  };
  int* H          = (int*)take((size_t)M * 4);          // 1.6 MB
  int* Hs         = (int*)take((size_t)(M + 1) * 4);    // 1.6 MB
  int* partials   = (int*)take((size_t)NB2 * 4);
  int* row_ptr    = (int*)take((size_t)(N + 1) * 4);
  float* nout     = (float*)take((size_t)N * 4);
  float* nin      = (float*)take((size_t)N * 4);
  int* flag       = (int*)take(4);
  unsigned* pack_d = (unsigned*)take((size_t)E * 4);    // 6.4 MB
  unsigned char* src_loc = (unsigned char*)take((size_t)E); // 1.6 MB
  int* csr_src    = (int*)take((size_t)E * 4);          // 6.4 MB
  unsigned short* x1h = (unsigned short*)take((size_t)N * DF * 2); // 25.6 MB
  unsigned short* h1h = (unsigned short*)take((size_t)N * DF * 2); // 25.6 MB
  unsigned short* aggh = (unsigned short*)take((size_t)N * DF * 2); // 25.6 MB
  unsigned short* Wswz = (unsigned short*)take(2 * 65536);          // 128 KiB
  (void)ws_size; (void)n_in; (void)out_size;

  hipMemsetAsync(flag, 0, 4, stream);
  detect_dtype_kernel<<<8, 256, 0, stream>>>((const unsigned*)ei, (long long)in_sizes[1], flag);

  part_count_kernel<<<PB, 256, 0, stream>>>(ei, E, nbuck, chunk, H, flag);
  chunk_sum_kernel<<<NB2, 1024, 0, stream>>>(H, partials, M);
  scan_partials_kernel<<<1, 64, 0, stream>>>(partials, NB2);
  scan_chunk_kernel<<<NB2, 1024, 0, stream>>>(H, partials, Hs, M);
  part_scatter_kernel<<<PB, 256, 0, stream>>>(ei, E, nbuck, chunk, Hs, pack_d, src_loc, flag);
  bucket_build_kernel<<<nbuck, 256, 0, stream>>>(pack_d, Hs, E, N, row_ptr, nin, csr_src);
  src_deg_kernel<<<nbuck, 256, 0, stream>>>(src_loc, Hs, nbuck, E, N, nout);

  w_prep_kernel<<<32, 256, 0, stream>>>(W1, W2, Wswz);

  // conv1 operand: x1h = bf16(in_feat * dout)
  int pb = (int)(((long long)N * DF / 8 + 255) / 256);
  prescale_kernel<<<pb, 256, 0, stream>>>(in_feat, nout, x1h, N);

  int ab = (N + 3) / 4;  // 4 waves (nodes) per 256-thread block
  // conv1: x1h -> aggh -> h1h = bf16((nin*(aggh@W1)+b1)*dout)
  aggregate_bf16_kernel<<<ab, 256, 0, stream>>>(x1h, row_ptr, csr_src, aggh, N);
  transform_mfma_kernel<1><<<512, 256, 0, stream>>>(aggh, Wswz, nin, b1, nout, h1h, N, ntiles);
  // conv2: h1h -> aggh -> out (f32)
  aggregate_bf16_kernel<<<ab, 256, 0, stream>>>(h1h, row_ptr, csr_src, aggh, N);
  transform_mfma_kernel<0><<<512, 256, 0, stream>>>(aggh, Wswz + 32768, nin, b2, nullptr, out, N, ntiles);
}